// Round 9
// baseline (287.468 us; speedup 1.0000x reference)
//
#include <hip/hip_runtime.h>
#include <hip/hip_bf16.h>
#include <math.h>

typedef short bf16x8 __attribute__((ext_vector_type(8)));
typedef float f32x4  __attribute__((ext_vector_type(4)));

#define GLOBAL_AS __attribute__((address_space(1)))
#define LDS_AS    __attribute__((address_space(3)))

__device__ __forceinline__ void async16(const void* g, void* l) {
  __builtin_amdgcn_global_load_lds((GLOBAL_AS void*)(g), (LDS_AS void*)(l), 16, 0, 0);
}

__device__ __forceinline__ unsigned short f2bf(float f){
  union { float f; unsigned u; } x; x.f = f;
  return (unsigned short)((x.u + 0x7fffu + ((x.u >> 16) & 1u)) >> 16);
}
__device__ __forceinline__ float bf2f(short s){
  union { unsigned u; float f; } x; x.u = ((unsigned)(unsigned short)s) << 16;
  return x.f;
}
__device__ __forceinline__ float gelu_f(float x){
  return 0.5f*x*(1.f+erff(x*0.70710678118654752f));
}

// ---------------- LayerNorm -> bf16 out ------------------------------------
__global__ __launch_bounds__(256) void ln_bf16(const float* __restrict__ in,
    const float* __restrict__ gg, const float* __restrict__ bb, short* __restrict__ out)
{
  const int row = blockIdx.x;
  const int tid = threadIdx.x;
  const float4 v = reinterpret_cast<const float4*>(in + (size_t)row*1024)[tid];
  float s  = v.x+v.y+v.z+v.w;
  float sq = v.x*v.x+v.y*v.y+v.z*v.z+v.w*v.w;
  #pragma unroll
  for (int off=32; off; off>>=1){ s += __shfl_xor(s,off); sq += __shfl_xor(sq,off); }
  __shared__ float ss[4], qs[4];
  const int wid = tid>>6, lane = tid&63;
  if (lane==0){ ss[wid]=s; qs[wid]=sq; }
  __syncthreads();
  s  = ss[0]+ss[1]+ss[2]+ss[3];
  sq = qs[0]+qs[1]+qs[2]+qs[3];
  const float mu  = s * (1.f/1024.f);
  const float var = sq*(1.f/1024.f) - mu*mu;
  const float rs  = rsqrtf(var + 1e-5f);
  const float4 g4 = reinterpret_cast<const float4*>(gg)[tid];
  const float4 b4 = reinterpret_cast<const float4*>(bb)[tid];
  ushort4 o;
  o.x = f2bf((v.x-mu)*rs*g4.x+b4.x);
  o.y = f2bf((v.y-mu)*rs*g4.y+b4.y);
  o.z = f2bf((v.z-mu)*rs*g4.z+b4.z);
  o.w = f2bf((v.w-mu)*rs*g4.w+b4.w);
  *reinterpret_cast<ushort4*>(out + (size_t)row*1024 + tid*4) = o;
}

// ------------- weight fp32 [K][N] -> bf16 transposed [N][K] (+optional add) -
__global__ __launch_bounds__(256) void conv_transpose(const float* __restrict__ in,
    short* __restrict__ out, int K, int N, const float* __restrict__ add, int addN)
{
  __shared__ float tile[32][33];
  const int n0 = blockIdx.x*32, k0 = blockIdx.y*32;
  const int r = threadIdx.x >> 3, c4 = (threadIdx.x & 7)*4;
  float4 v = *reinterpret_cast<const float4*>(&in[(size_t)(k0+r)*N + n0 + c4]);
  if (add && (n0 + c4) < addN) {
    const float* ap = &add[(size_t)(k0+r)*addN + n0 + c4];
    v.x += ap[0]; v.y += ap[1]; v.z += ap[2]; v.w += ap[3];
  }
  tile[r][c4+0]=v.x; tile[r][c4+1]=v.y; tile[r][c4+2]=v.z; tile[r][c4+3]=v.w;
  __syncthreads();
  ushort4 o;
  o.x = f2bf(tile[c4+0][r]); o.y = f2bf(tile[c4+1][r]);
  o.z = f2bf(tile[c4+2][r]); o.w = f2bf(tile[c4+3][r]);
  *reinterpret_cast<ushort4*>(&out[(size_t)(n0+r)*K + k0 + c4]) = o;
}

// ---------------- bias vector for fused qkv+ug (4352 wide) ------------------
__global__ __launch_bounds__(256) void init_ball(const float* __restrict__ b_ug,
                                                 float* __restrict__ b_all)
{
  const int i = blockIdx.x*256 + threadIdx.x;
  float v = 0.f;
  if (i >= 3072 && i < 4224) v = b_ug[i-3072];
  b_all[i] = v;
}

// ======= 256x256 tile, BK=32, 8 waves, 3-buffer deep-prefetch pipeline ======
// EPI: 0 = plain bf16 out; 1 = bias+gelu bf16 out;
//      2 = fused qkv+ug: col<3072 -> qkv bf16; <3200 -> drive f32; <4224 -> gate bf16
template<int EPI>
__global__ __launch_bounds__(512) void gemm256(
    const short* __restrict__ A, const short* __restrict__ Bt,
    const float* __restrict__ bias, short* __restrict__ Cout,
    float* __restrict__ drive, short* __restrict__ gate,
    int M, int N, int K)
{
  extern __shared__ char lds[];     // 3 bufs x (A 16KB + B 16KB) = 96KB
  const int tid = threadIdx.x;
  const int ln = tid & 63, w = tid >> 6;
  const int wr = w >> 2, wc = w & 3;          // 2 x 4 wave grid
  const int lane15 = ln & 15, lgrp = ln >> 4;

  const int gx = gridDim.x;
  const int nwg = gx * gridDim.y;
  int id = blockIdx.y * gx + blockIdx.x;
  if ((nwg & 7) == 0) { const int cpx = nwg >> 3; id = (id & 7) * cpx + (id >> 3); }
  const int m0 = (id / gx) * 256, n0 = (id % gx) * 256;

  const int NT = K >> 5;

  f32x4 acc[8][4];
  #pragma unroll
  for (int i=0;i<8;i++)
    #pragma unroll
    for (int j=0;j<4;j++) acc[i][j] = (f32x4){0.f,0.f,0.f,0.f};

  // one instruction per call; p 0,1 = A rows 0-127/128-255; p 2,3 = B likewise
  #define STG32(kt_, p_) { \
    char* buf_ = lds + ((kt_) % 3) * 32768; \
    const int slot_ = ((p_) & 1) * 512 + tid; \
    const int row_ = slot_ >> 2, blk_ = slot_ & 3; \
    const int sblk_ = blk_ ^ (row_ & 3); \
    if ((p_) < 2) async16(A  + (size_t)(m0 + row_)*K + ((kt_) << 5) + sblk_*8, buf_ + slot_*16); \
    else          async16(Bt + (size_t)(n0 + row_)*K + ((kt_) << 5) + sblk_*8, buf_ + 16384 + slot_*16); }

  // prologue: tiles 0 and 1 fully staged (depth 2)
  STG32(0,0); STG32(0,1); STG32(0,2); STG32(0,3);
  if (NT > 1) { STG32(1,0); STG32(1,1); STG32(1,2); STG32(1,3); }

  for (int kt = 0; kt < NT; ++kt) {
    // boundary: tile kt's loads were issued a full tile ago -> near-free wait.
    // LAST tile: its own 4 loads are the only outstanding -> must drain fully.
    if (kt+1 < NT) asm volatile("s_waitcnt vmcnt(4)" ::: "memory");
    else           asm volatile("s_waitcnt vmcnt(0)" ::: "memory");
    __builtin_amdgcn_s_barrier();
    __builtin_amdgcn_sched_barrier(0);
    char* rdA = lds + (kt % 3) * 32768;
    char* rdB = rdA + 16384;
    const bool more = (kt + 2 < NT);

    bf16x8 bfr[4];
    #pragma unroll
    for (int ni = 0; ni < 4; ni++) {
      const int row = wc*64 + ni*16 + lane15;
      const int b = lgrp ^ (row & 3);
      bfr[ni] = *reinterpret_cast<const bf16x8*>(rdB + (row*4 + b)*16);
    }
    if (more) { STG32(kt+2, 2); STG32(kt+2, 3); }
    #pragma unroll
    for (int mq = 0; mq < 2; ++mq) {
      bf16x8 af[4];
      #pragma unroll
      for (int mi = 0; mi < 4; mi++) {
        const int row = wr*128 + (mq*4+mi)*16 + lane15;
        const int b = lgrp ^ (row & 3);
        af[mi] = *reinterpret_cast<const bf16x8*>(rdA + (row*4 + b)*16);
      }
      if (more) STG32(kt+2, mq);
      __builtin_amdgcn_s_setprio(1);
      #pragma unroll
      for (int mi = 0; mi < 4; mi++)
        #pragma unroll
        for (int ni = 0; ni < 4; ni++)
          acc[mq*4+mi][ni] = __builtin_amdgcn_mfma_f32_16x16x32_bf16(
              af[mi], bfr[ni], acc[mq*4+mi][ni], 0, 0, 0);
      __builtin_amdgcn_s_setprio(0);
    }
  }
  #undef STG32

  #pragma unroll
  for (int ni = 0; ni < 4; ni++) {
    const int col = n0 + wc*64 + ni*16 + lane15;
    const float bv = bias ? bias[col] : 0.f;
    #pragma unroll
    for (int mi = 0; mi < 8; mi++) {
      #pragma unroll
      for (int r = 0; r < 4; r++) {
        const int row = m0 + wr*128 + mi*16 + lgrp*4 + r;
        float v = acc[mi][ni][r] + bv;
        if (EPI == 0) {
          Cout[(size_t)row*N + col] = (short)f2bf(v);
        } else if (EPI == 1) {
          Cout[(size_t)row*N + col] = (short)f2bf(gelu_f(v));
        } else {
          if (col < 3072)      Cout[(size_t)row*3072 + col] = (short)f2bf(v);
          else if (col < 3200) drive[(size_t)row*128 + (col-3072)] = v;
          else if (col < 4224) gate[(size_t)row*1024 + (col-3200)] = (short)f2bf(1.f/(1.f+__expf(-v)));
        }
      }
    }
  }
}

// ====== 64x128 tile, BK=64, 4 waves, 3-buffer deep-prefetch pipeline ========
// EPI 3 = RES: out = acc + bias + out  (fp32, in-place resid)
template<int MT, int EPI>
__global__ __launch_bounds__(256) void gemm128(
    const short* __restrict__ A, const short* __restrict__ Bt,
    const float* __restrict__ bias,
    void* __restrict__ Cout, int M, int N, int K)
{
  constexpr int BM  = MT * 32;
  constexpr int ABY = BM * 128;         // A buf bytes
  constexpr int BUFS = ABY + 16384;     // one buffer (A+B)
  constexpr int MPQ = MT / 2;
  extern __shared__ char lds[];         // 3 * BUFS
  const int tid = threadIdx.x;
  const int ln = tid & 63, w = tid >> 6;
  const int wr = w >> 1, wc = w & 1;
  const int lane15 = ln & 15, lgrp = ln >> 4;

  const int gx = gridDim.x;
  const int nwg = gx * gridDim.y;
  int id = blockIdx.y * gx + blockIdx.x;
  if ((nwg & 7) == 0) { const int cpx = nwg >> 3; id = (id & 7) * cpx + (id >> 3); }
  const int m0 = (id / gx) * BM, n0 = (id % gx) * 128;

  const int NT = K >> 6;

  f32x4 acc[MT][4];
  #pragma unroll
  for (int i=0;i<MT;i++)
    #pragma unroll
    for (int j=0;j<4;j++) acc[i][j] = (f32x4){0.f,0.f,0.f,0.f};

  #define STG(kt_, p_) { \
    char* bA_ = lds + ((kt_) % 3) * BUFS; \
    char* bB_ = bA_ + ABY; \
    const int slot_ = (p_)*256 + tid; \
    const int row_ = slot_ >> 3, blk_ = slot_ & 7; \
    const int sblk_ = blk_ ^ (row_ & 7); \
    if ((p_) < MT) async16(A + (size_t)(m0+row_)*K + ((kt_) << 6) + sblk_*8, bA_ + slot_*16); \
    async16(Bt + (size_t)(n0+row_)*K + ((kt_) << 6) + sblk_*8, bB_ + slot_*16); }

  STG(0,0); STG(0,1); STG(0,2); STG(0,3);
  if (NT > 1) { STG(1,0); STG(1,1); STG(1,2); STG(1,3); }

  for (int kt = 0; kt < NT; ++kt) {
    if (kt+1 < NT) asm volatile("s_waitcnt vmcnt(6)" ::: "memory");
    else           asm volatile("s_waitcnt vmcnt(0)" ::: "memory");
    __builtin_amdgcn_s_barrier();
    __builtin_amdgcn_sched_barrier(0);
    char* rdA = lds + (kt % 3) * BUFS;
    char* rdB = rdA + ABY;
    const bool more = (kt + 2 < NT);

    bf16x8 bfr[4][2];
    #pragma unroll
    for (int ni = 0; ni < 4; ni++) {
      const int row = wc*64 + ni*16 + lane15;
      #pragma unroll
      for (int ks = 0; ks < 2; ks++) {
        const int b = (ks*4 + lgrp) ^ (row & 7);
        bfr[ni][ks] = *reinterpret_cast<const bf16x8*>(rdB + (row*8 + b)*16);
      }
    }
    if (more) { STG(kt+2, 0); STG(kt+2, 1); }
    #pragma unroll
    for (int mq = 0; mq < 2; ++mq) {
      bf16x8 af[MPQ][2];
      #pragma unroll
      for (int mi = 0; mi < MPQ; mi++) {
        const int row = wr*(MT*16) + (mq*MPQ+mi)*16 + lane15;
        #pragma unroll
        for (int ks = 0; ks < 2; ks++) {
          const int b = (ks*4 + lgrp) ^ (row & 7);
          af[mi][ks] = *reinterpret_cast<const bf16x8*>(rdA + (row*8 + b)*16);
        }
      }
      if (more) STG(kt+2, 2+mq);
      __builtin_amdgcn_s_setprio(1);
      #pragma unroll
      for (int mi = 0; mi < MPQ; mi++)
        #pragma unroll
        for (int ni = 0; ni < 4; ni++)
          #pragma unroll
          for (int ks = 0; ks < 2; ks++)
            acc[mq*MPQ+mi][ni] = __builtin_amdgcn_mfma_f32_16x16x32_bf16(
                af[mi][ks], bfr[ni][ks], acc[mq*MPQ+mi][ni], 0, 0, 0);
      __builtin_amdgcn_s_setprio(0);
    }
  }
  #undef STG

  #pragma unroll
  for (int ni = 0; ni < 4; ni++) {
    const int col = n0 + wc*64 + ni*16 + lane15;
    const float bv = bias ? bias[col] : 0.f;
    #pragma unroll
    for (int mi = 0; mi < MT; mi++) {
      #pragma unroll
      for (int r = 0; r < 4; r++) {
        const int row = m0 + wr*(MT*16) + mi*16 + lgrp*4 + r;
        const float v = acc[mi][ni][r] + bv;
        float* o = (float*)Cout;
        o[(size_t)row*N + col] = v + o[(size_t)row*N + col];
      }
    }
  }
}

// ====== Fused W_O + C_w combine: out = x + g*(attn@WO+bO) + (1-g)*(st@Cw) ===
__global__ __launch_bounds__(256) void wo_comb(
    const short* __restrict__ A1, const short* __restrict__ B1t,   // attn, wT_o
    const short* __restrict__ A2, const short* __restrict__ B2t,   // st, wT_c
    const float* __restrict__ bias, const float* __restrict__ e_x,
    const short* __restrict__ e_g, float* __restrict__ Cout)
{
  constexpr int ABY = 8192;        // 64*64*2
  constexpr int BUFS = ABY + 16384;
  extern __shared__ char lds[];    // 3 * BUFS = 72KB
  const int tid = threadIdx.x;
  const int ln = tid & 63, w = tid >> 6;
  const int wr = w >> 1, wc = w & 1;
  const int lane15 = ln & 15, lgrp = ln >> 4;
  const int K = 1024, N = 1024;

  const int gx = gridDim.x;
  const int nwg = gx * gridDim.y;
  int id = blockIdx.y * gx + blockIdx.x;
  if ((nwg & 7) == 0) { const int cpx = nwg >> 3; id = (id & 7) * cpx + (id >> 3); }
  const int m0 = (id / gx) * 64, n0 = (id % gx) * 128;

  f32x4 acc1[2][4], acc2[2][4];
  #pragma unroll
  for (int i=0;i<2;i++)
    #pragma unroll
    for (int j=0;j<4;j++){ acc1[i][j] = (f32x4){0.f,0.f,0.f,0.f}; acc2[i][j] = (f32x4){0.f,0.f,0.f,0.f}; }

  #define STGW(Asrc_, Bsrc_, AK_, kb_, bidx_, p_) { \
    char* bA_ = lds + (bidx_) * BUFS; \
    char* bB_ = bA_ + ABY; \
    const int slot_ = (p_)*256 + tid; \
    const int row_ = slot_ >> 3, blk_ = slot_ & 7; \
    const int sblk_ = blk_ ^ (row_ & 7); \
    if ((p_) < 2) async16(Asrc_ + (size_t)(m0+row_)*(AK_) + (kb_) + sblk_*8, bA_ + slot_*16); \
    async16(Bsrc_ + (size_t)(n0+row_)*(AK_) + (kb_) + sblk_*8, bB_ + slot_*16); }

  STGW(A1, B1t, K, 0,  0, 0); STGW(A1, B1t, K, 0,  0, 1); STGW(A1, B1t, K, 0,  0, 2); STGW(A1, B1t, K, 0,  0, 3);
  STGW(A1, B1t, K, 64, 1, 0); STGW(A1, B1t, K, 64, 1, 1); STGW(A1, B1t, K, 64, 1, 2); STGW(A1, B1t, K, 64, 1, 3);

  const int NT = 16;
  for (int kt = 0; kt < NT; ++kt) {
    if (kt+1 < NT) asm volatile("s_waitcnt vmcnt(6)" ::: "memory");
    else           asm volatile("s_waitcnt vmcnt(0)" ::: "memory");
    __builtin_amdgcn_s_barrier();
    __builtin_amdgcn_sched_barrier(0);
    char* rdA = lds + (kt % 3) * BUFS;
    char* rdB = rdA + ABY;
    const bool more = (kt + 2 < NT);
    const int wb = (kt + 2) % 3;

    bf16x8 bfr[4][2];
    #pragma unroll
    for (int ni = 0; ni < 4; ni++) {
      const int row = wc*64 + ni*16 + lane15;
      #pragma unroll
      for (int ks = 0; ks < 2; ks++) {
        const int b = (ks*4 + lgrp) ^ (row & 7);
        bfr[ni][ks] = *reinterpret_cast<const bf16x8*>(rdB + (row*8 + b)*16);
      }
    }
    if (more) { STGW(A1, B1t, K, (kt+2)<<6, wb, 0); STGW(A1, B1t, K, (kt+2)<<6, wb, 1); }
    #pragma unroll
    for (int mq = 0; mq < 2; ++mq) {
      bf16x8 af[2];
      {
        const int row = wr*32 + mq*16 + lane15;
        #pragma unroll
        for (int ks = 0; ks < 2; ks++) {
          const int b = (ks*4 + lgrp) ^ (row & 7);
          af[ks] = *reinterpret_cast<const bf16x8*>(rdA + (row*8 + b)*16);
        }
      }
      if (more) STGW(A1, B1t, K, (kt+2)<<6, wb, 2+mq);
      __builtin_amdgcn_s_setprio(1);
      #pragma unroll
      for (int ni = 0; ni < 4; ni++)
        #pragma unroll
        for (int ks = 0; ks < 2; ks++)
          acc1[mq][ni] = __builtin_amdgcn_mfma_f32_16x16x32_bf16(
              af[ks], bfr[ni][ks], acc1[mq][ni], 0, 0, 0);
      __builtin_amdgcn_s_setprio(0);
    }
  }

  // ---- phase 2: acc2 = st @ Cw (K2 = 128, two 64-K tiles, no pipeline) ----
  __builtin_amdgcn_s_barrier();          // all waves done reading main bufs
  STGW(A2, B2t, 128, 0,  0, 0); STGW(A2, B2t, 128, 0,  0, 1); STGW(A2, B2t, 128, 0,  0, 2); STGW(A2, B2t, 128, 0,  0, 3);
  STGW(A2, B2t, 128, 64, 1, 0); STGW(A2, B2t, 128, 64, 1, 1); STGW(A2, B2t, 128, 64, 1, 2); STGW(A2, B2t, 128, 64, 1, 3);
  asm volatile("s_waitcnt vmcnt(0)" ::: "memory");
  __builtin_amdgcn_s_barrier();

  #pragma unroll
  for (int t2 = 0; t2 < 2; ++t2) {
    char* rdA = lds + t2*BUFS; char* rdB = rdA + ABY;
    bf16x8 bfr2[4][2];
    #pragma unroll
    for (int ni = 0; ni < 4; ni++) {
      const int brow = wc*64 + ni*16 + lane15;
      #pragma unroll
      for (int ks = 0; ks < 2; ks++) {
        const int b = (ks*4 + lgrp) ^ (brow & 7);
        bfr2[ni][ks] = *reinterpret_cast<const bf16x8*>(rdB + (brow*8 + b)*16);
      }
    }
    #pragma unroll
    for (int mi = 0; mi < 2; mi++) {
      bf16x8 af[2];
      const int row = wr*32 + mi*16 + lane15;
      #pragma unroll
      for (int ks = 0; ks < 2; ks++) {
        const int b = (ks*4 + lgrp) ^ (row & 7);
        af[ks] = *reinterpret_cast<const bf16x8*>(rdA + (row*8 + b)*16);
      }
      #pragma unroll
      for (int ni = 0; ni < 4; ni++)
        #pragma unroll
        for (int ks = 0; ks < 2; ks++)
          acc2[mi][ni] = __builtin_amdgcn_mfma_f32_16x16x32_bf16(af[ks], bfr2[ni][ks], acc2[mi][ni], 0, 0, 0);
    }
  }
  #undef STGW

  #pragma unroll
  for (int ni = 0; ni < 4; ni++) {
    const int col = n0 + wc*64 + ni*16 + lane15;
    const float bv = bias[col];
    #pragma unroll
    for (int mi = 0; mi < 2; mi++) {
      #pragma unroll
      for (int r = 0; r < 4; r++) {
        const int row = m0 + wr*32 + mi*16 + lgrp*4 + r;
        const float g = bf2f(e_g[(size_t)row*1024 + col]);
        Cout[(size_t)row*N + col] = e_x[(size_t)row*1024 + col]
            + g*(acc1[mi][ni][r] + bv) + (1.f-g)*acc2[mi][ni][r];
      }
    }
  }
}

// ---------------- Flash sliding-window attention (MFMA, bf16) ---------------
#define ATS 72
__global__ __launch_bounds__(256) void attn_mfma(const short* __restrict__ qkv,
                                                 short* __restrict__ attn_out)
{
  __shared__ short Qs[64*ATS];
  __shared__ short Ks[64*ATS];
  __shared__ short Vt[64*ATS];
  __shared__ short Ps[4][16*ATS];
  const int tid = threadIdx.x;
  const int ln = tid & 63, w = tid >> 6;
  const int qt0 = (blockIdx.x >> 4) * 64;
  const int h = blockIdx.x & 15;

  {
    const int jr = tid >> 3, d0 = (tid & 7) * 8;
    #pragma unroll
    for (int p = 0; p < 2; p++) {
      const int j = jr + p*32;
      const bf16x8 v = *reinterpret_cast<const bf16x8*>(&qkv[(size_t)(qt0 + j)*3072 + h*64 + d0]);
      const int blk = (d0 >> 3) ^ (j & 7);
      *reinterpret_cast<bf16x8*>(&Qs[j*ATS + blk*8]) = v;
    }
  }

  float mrow[4], lrow[4];
  f32x4 oacc[4];
  #pragma unroll
  for (int r=0;r<4;r++){ mrow[r] = -1e30f; lrow[r] = 0.f; }
  #pragma unroll
  for (int df=0;df<4;df++) oacc[df] = (f32x4){0.f,0.f,0.f,0.f};

  const int qrow_lane = w*16 + (ln>>4)*4;
  const int qtile = qt0 >> 6;
  const int cstart = (qtile >= 4) ? 0 : (4 - qtile);

  for (int c = cstart; c < 5; c++) {
    const int cs = qt0 - 256 + c*64;
    {
      const int jr = tid >> 3, d0 = (tid & 7) * 8;
      #pragma unroll
      for (int p = 0; p < 2; p++) {
        const int j = jr + p*32;
        const size_t krow = (size_t)(cs + j)*3072 + h*64;
        const bf16x8 kv = *reinterpret_cast<const bf16x8*>(&qkv[krow + 1024 + d0]);
        const int blk = (d0>>3) ^ (j & 7);
        *reinterpret_cast<bf16x8*>(&Ks[j*ATS + blk*8]) = kv;
        const bf16x8 vv = *reinterpret_cast<const bf16x8*>(&qkv[krow + 2048 + d0]);
        #pragma unroll
        for (int i = 0; i < 8; i++) {
          const int d = d0 + i;
          const int jb = (j >> 3) ^ ((d >> 3) & 7);
          Vt[d*ATS + jb*8 + (j & 7)] = ((const short*)&vv)[i];
        }
      }
    }
    __syncthreads();

    bf16x8 aq[2];
    #pragma unroll
    for (int ks=0; ks<2; ks++){
      const int row = w*16 + (ln & 15);
      const int b = (ks*4 + (ln>>4)) ^ (row & 7);
      aq[ks] = *reinterpret_cast<const bf16x8*>(&Qs[row*ATS + b*8]);
    }
    float sv[4][4];
    #pragma unroll
    for (int nf=0; nf<4; nf++){
      const int krow = nf*16 + (ln & 15);
      f32x4 s = (f32x4){0.f,0.f,0.f,0.f};
      #pragma unroll
      for (int ks=0; ks<2; ks++){
        const int b = (ks*4 + (ln>>4)) ^ (krow & 7);
        const bf16x8 bk = *reinterpret_cast<const bf16x8*>(&Ks[krow*ATS + b*8]);
        s = __builtin_amdgcn_mfma_f32_16x16x32_bf16(aq[ks], bk, s, 0, 0, 0);
      }
      const int k_abs = cs + nf*16 + (ln & 15);
      #pragma unroll
      for (int r=0;r<4;r++){
        const int t_abs = qt0 + qrow_lane + r;
        const bool valid = (k_abs <= t_abs) && (k_abs >= t_abs - 255);
        sv[nf][r] = valid ? s[r]*0.125f : -1e30f;
      }
    }
    float cm[4], alpha[4], rs[4];
    #pragma unroll
    for (int r=0;r<4;r++){
      cm[r] = fmaxf(fmaxf(sv[0][r],sv[1][r]), fmaxf(sv[2][r],sv[3][r]));
      #pragma unroll
      for (int off=1; off<16; off<<=1) cm[r] = fmaxf(cm[r], __shfl_xor(cm[r], off));
      const float mnew = fmaxf(mrow[r], cm[r]);
      alpha[r] = __expf(mrow[r] - mnew);
      mrow[r] = mnew;
      rs[r] = 0.f;
    }
    #pragma unroll
    for (int nf=0; nf<4; nf++){
      const int pcol = nf*16 + (ln & 15);
      #pragma unroll
      for (int r=0;r<4;r++){
        const float p = (sv[nf][r] <= -1e29f) ? 0.f : __expf(sv[nf][r] - mrow[r]);
        rs[r] += p;
        const int prow = (ln>>4)*4 + r;
        const int pb = (pcol>>3) ^ (prow & 7);
        Ps[w][prow*ATS + pb*8 + (pcol & 7)] = (short)f2bf(p);
      }
    }
    #pragma unroll
    for (int r=0;r<4;r++){
      #pragma unroll
      for (int off=1; off<16; off<<=1) rs[r] += __shfl_xor(rs[r], off);
      lrow[r] = lrow[r]*alpha[r] + rs[r];
      #pragma unroll
      for (int df=0; df<4; df++) oacc[df][r] *= alpha[r];
    }
    bf16x8 ap[2];
    #pragma unroll
    for (int ks=0; ks<2; ks++){
      const int prow = (ln & 15);
      const int b = (ks*4 + (ln>>4)) ^ (prow & 7);
      ap[ks] = *reinterpret_cast<const bf16x8*>(&Ps[w][prow*ATS + b*8]);
    }
    #pragma unroll
    for (int df=0; df<4; df++){
      const int vrow = df*16 + (ln & 15);
      #pragma unroll
      for (int ks=0; ks<2; ks++){
        const int b = (ks*4 + (ln>>4)) ^ ((vrow>>3) & 7);
        const bf16x8 bv = *reinterpret_cast<const bf16x8*>(&Vt[vrow*ATS + b*8]);
        oacc[df] = __builtin_amdgcn_mfma_f32_16x16x32_bf16(ap[ks], bv, oacc[df], 0, 0, 0);
      }
    }
    __syncthreads();
  }

  #pragma unroll
  for (int df=0; df<4; df++)
    #pragma unroll
    for (int r=0; r<4; r++){
      const int t = qt0 + qrow_lane + r;
      const int d = df*16 + (ln & 15);
      attn_out[(size_t)t*1024 + h*64 + d] = (short)f2bf(oacc[df][r] / lrow[r]);
    }
}

// ---------------- SSM scan as 16-tap convolution (compact drive) ------------
__global__ __launch_bounds__(256) void scan_kernel(const float* __restrict__ drive,
    const float* __restrict__ Aa, short* __restrict__ states)
{
  const int idx = blockIdx.x*256 + threadIdx.x;
  const int t = idx >> 7, s = idx & 127;
  const float a = Aa[s];
  float acc = 0.f, pw = 1.f;
  const int kmax = (t+1 < 16) ? (t+1) : 16;
  for (int k=0;k<kmax;k++){
    acc = fmaf(pw, drive[(size_t)(t-k)*128 + s], acc);
    pw *= a;
  }
  states[idx] = (short)f2bf(acc);
}

extern "C" void kernel_launch(void* const* d_in, const int* in_sizes, int n_in,
                              void* d_out, int out_size, void* d_ws, size_t ws_size,
                              hipStream_t stream)
{
  const float* x     = (const float*)d_in[0];
  const float* ln1_g = (const float*)d_in[1];
  const float* ln1_b = (const float*)d_in[2];
  const float* ln2_g = (const float*)d_in[3];
  const float* ln2_b = (const float*)d_in[4];
  const float* W_qkv = (const float*)d_in[5];
  const float* W_O   = (const float*)d_in[6];
  const float* b_O   = (const float*)d_in[7];
  const float* W_ug  = (const float*)d_in[8];
  const float* b_ug  = (const float*)d_in[9];
  const float* B_w   = (const float*)d_in[10];
  const float* A     = (const float*)d_in[11];
  const float* C_w   = (const float*)d_in[12];
  const float* W1    = (const float*)d_in[13];
  const float* b1    = (const float*)d_in[14];
  const float* W2    = (const float*)d_in[15];
  const float* b2    = (const float*)d_in[16];
  float* out = (float*)d_out;
  char* ws = (char*)d_ws;

  short* qkv_bf = (short*)(ws + 0);          // 24MB
  short* attn_bf= (short*)(ws + 25165824);   // 8MB
  short* xn_bf  = (short*)(ws + 33554432);   // 8MB (h aliases)
  short* g_bf   = (short*)(ws + 41943040);   // 8MB  gate (sigmoid, bf16)
  float* drive  = (float*)(ws + 50331648);   // 2MB  fp32 [4096][128]
  short* st_bf  = (short*)(ws + 52428800);   // 1MB
  float* b_all  = (float*)(ws + 53477376);   // 64KB reserve
  short* wT_all = (short*)(ws + 53542912);   // [4352][1024] 8.9MB (9MB reserve)
  short* wT_o   = (short*)(ws + 62980096);   // 2MB
  short* wT_c   = (short*)(ws + 65077248);   // 0.25MB
  short* wT_1   = (short*)(ws + 65339392);   // 8MB
  short* wT_2   = (short*)(ws + 73728000);   // 8MB
  short* mid_bf = (short*)(ws + 0);          // 32MB alias (dead qkv+attn)
  short* h_bf   = xn_bf;

  static bool attr_done = false;
  if (!attr_done) {
    hipFuncSetAttribute((const void*)gemm256<1>, hipFuncAttributeMaxDynamicSharedMemorySize, 98304);
    hipFuncSetAttribute((const void*)gemm256<2>, hipFuncAttributeMaxDynamicSharedMemorySize, 98304);
    hipFuncSetAttribute((const void*)(gemm128<2,3>), hipFuncAttributeMaxDynamicSharedMemorySize, 73728);
    hipFuncSetAttribute((const void*)wo_comb, hipFuncAttributeMaxDynamicSharedMemorySize, 73728);
    attr_done = true;
  }

  // weights: fused [4352][1024] = qkv^T | ug^T(+B_w) | zero pad
  conv_transpose<<<dim3(96,32),  256, 0, stream>>>(W_qkv, wT_all, 1024, 3072, nullptr, 0);
  conv_transpose<<<dim3(36,32),  256, 0, stream>>>(W_ug,  wT_all + (size_t)3072*1024, 1024, 1152, B_w, 128);
  hipMemsetAsync(wT_all + (size_t)4224*1024, 0, (size_t)128*1024*2, stream);
  init_ball<<<17, 256, 0, stream>>>(b_ug, b_all);
  conv_transpose<<<dim3(32,32),  256, 0, stream>>>(W_O,   wT_o,   1024, 1024, nullptr, 0);
  conv_transpose<<<dim3(32,4),   256, 0, stream>>>(C_w,   wT_c,   128,  1024, nullptr, 0);
  conv_transpose<<<dim3(128,32), 256, 0, stream>>>(W1,    wT_1,   1024, 4096, nullptr, 0);
  conv_transpose<<<dim3(32,128), 256, 0, stream>>>(W2,    wT_2,   4096, 1024, nullptr, 0);

  ln_bf16<<<4096, 256, 0, stream>>>(x, ln1_g, ln1_b, xn_bf);
  gemm256<2><<<dim3(17,16), 512, 98304, stream>>>(xn_bf, wT_all, b_all, qkv_bf, drive, g_bf, 4096, 4352, 1024);
  attn_mfma<<<1024, 256, 0, stream>>>(qkv_bf, attn_bf);
  scan_kernel<<<2048, 256, 0, stream>>>(drive, A, st_bf);
  wo_comb<<<dim3(8,64), 256, 73728, stream>>>(attn_bf, wT_o, st_bf, wT_c, b_O, x, g_bf, out);
  ln_bf16<<<4096, 256, 0, stream>>>(out, ln2_g, ln2_b, h_bf);
  gemm256<1><<<dim3(16,16), 512, 98304, stream>>>(h_bf, wT_1, b1, mid_bf, nullptr, nullptr, 4096, 4096, 1024);
  gemm128<2,3><<<dim3(8,64), 256, 73728, stream>>>(mid_bf, wT_2, b2, out, 4096, 1024, 4096);
}

// Round 10
// 284.098 us; speedup vs baseline: 1.0119x; 1.0119x over previous
//
#include <hip/hip_runtime.h>
#include <hip/hip_bf16.h>
#include <math.h>

typedef short bf16x8 __attribute__((ext_vector_type(8)));
typedef float f32x4  __attribute__((ext_vector_type(4)));

#define GLOBAL_AS __attribute__((address_space(1)))
#define LDS_AS    __attribute__((address_space(3)))

__device__ __forceinline__ void async16(const void* g, void* l) {
  __builtin_amdgcn_global_load_lds((GLOBAL_AS void*)(g), (LDS_AS void*)(l), 16, 0, 0);
}

__device__ __forceinline__ unsigned short f2bf(float f){
  union { float f; unsigned u; } x; x.f = f;
  return (unsigned short)((x.u + 0x7fffu + ((x.u >> 16) & 1u)) >> 16);
}
__device__ __forceinline__ float bf2f(short s){
  union { unsigned u; float f; } x; x.u = ((unsigned)(unsigned short)s) << 16;
  return x.f;
}
__device__ __forceinline__ float gelu_f(float x){
  return 0.5f*x*(1.f+erff(x*0.70710678118654752f));
}

// ---------------- LayerNorm -> bf16 out ------------------------------------
__global__ __launch_bounds__(256) void ln_bf16(const float* __restrict__ in,
    const float* __restrict__ gg, const float* __restrict__ bb, short* __restrict__ out)
{
  const int row = blockIdx.x;
  const int tid = threadIdx.x;
  const float4 v = reinterpret_cast<const float4*>(in + (size_t)row*1024)[tid];
  float s  = v.x+v.y+v.z+v.w;
  float sq = v.x*v.x+v.y*v.y+v.z*v.z+v.w*v.w;
  #pragma unroll
  for (int off=32; off; off>>=1){ s += __shfl_xor(s,off); sq += __shfl_xor(sq,off); }
  __shared__ float ss[4], qs[4];
  const int wid = tid>>6, lane = tid&63;
  if (lane==0){ ss[wid]=s; qs[wid]=sq; }
  __syncthreads();
  s  = ss[0]+ss[1]+ss[2]+ss[3];
  sq = qs[0]+qs[1]+qs[2]+qs[3];
  const float mu  = s * (1.f/1024.f);
  const float var = sq*(1.f/1024.f) - mu*mu;
  const float rs  = rsqrtf(var + 1e-5f);
  const float4 g4 = reinterpret_cast<const float4*>(gg)[tid];
  const float4 b4 = reinterpret_cast<const float4*>(bb)[tid];
  ushort4 o;
  o.x = f2bf((v.x-mu)*rs*g4.x+b4.x);
  o.y = f2bf((v.y-mu)*rs*g4.y+b4.y);
  o.z = f2bf((v.z-mu)*rs*g4.z+b4.z);
  o.w = f2bf((v.w-mu)*rs*g4.w+b4.w);
  *reinterpret_cast<ushort4*>(out + (size_t)row*1024 + tid*4) = o;
}

// ------------- weight fp32 [K][N] -> bf16 transposed [N][K] (+optional add) -
__global__ __launch_bounds__(256) void conv_transpose(const float* __restrict__ in,
    short* __restrict__ out, int K, int N, const float* __restrict__ add, int addN)
{
  __shared__ float tile[32][33];
  const int n0 = blockIdx.x*32, k0 = blockIdx.y*32;
  const int r = threadIdx.x >> 3, c4 = (threadIdx.x & 7)*4;
  float4 v = *reinterpret_cast<const float4*>(&in[(size_t)(k0+r)*N + n0 + c4]);
  if (add && (n0 + c4) < addN) {
    const float* ap = &add[(size_t)(k0+r)*addN + n0 + c4];
    v.x += ap[0]; v.y += ap[1]; v.z += ap[2]; v.w += ap[3];
  }
  tile[r][c4+0]=v.x; tile[r][c4+1]=v.y; tile[r][c4+2]=v.z; tile[r][c4+3]=v.w;
  __syncthreads();
  ushort4 o;
  o.x = f2bf(tile[c4+0][r]); o.y = f2bf(tile[c4+1][r]);
  o.z = f2bf(tile[c4+2][r]); o.w = f2bf(tile[c4+3][r]);
  *reinterpret_cast<ushort4*>(&out[(size_t)(n0+r)*K + k0 + c4]) = o;
}

// ---------------- bias vector for fused qkv+ug (4352 wide) ------------------
__global__ __launch_bounds__(256) void init_ball(const float* __restrict__ b_ug,
                                                 float* __restrict__ b_all)
{
  const int i = blockIdx.x*256 + threadIdx.x;
  float v = 0.f;
  if (i >= 3072 && i < 4224) v = b_ug[i-3072];
  b_all[i] = v;
}

// ======= 256x256 tile, BK=64, 8 waves, m201 8-phase half-tile schedule ======
// LDS: A dbuf 2x32KB @0, B dbuf 2x32KB @65536. Half-tiles are interleaved
// row-groups (A: 64-row groups, B: 32-row groups) so each half is consumed in
// exactly one phase by ALL waves. vmcnt(6) at phases 4/8 only.
// EPI: 1 = bias+gelu bf16 out
//      2 = fused qkv+ug: col<3072 qkv bf16; <3200 drive f32; <4224 gate bf16
template<int EPI>
__global__ __launch_bounds__(512) void gemm256(
    const short* __restrict__ A, const short* __restrict__ Bt,
    const float* __restrict__ bias, short* __restrict__ Cout,
    float* __restrict__ drive, short* __restrict__ gate,
    int M, int N, int K)
{
  extern __shared__ char lds[];
  const int tid = threadIdx.x;
  const int ln = tid & 63, w = tid >> 6;
  const int wr = w >> 2, wc = w & 3;          // 2 x 4 wave grid
  const int lane15 = ln & 15, lgrp = ln >> 4;

  const int gx = gridDim.x;
  const int nwg = gx * gridDim.y;
  int id = blockIdx.y * gx + blockIdx.x;
  if ((nwg & 7) == 0) { const int cpx = nwg >> 3; id = (id & 7) * cpx + (id >> 3); }
  const int m0 = (id / gx) * 256, n0 = (id % gx) * 256;

  const int NT = K >> 6;      // 16
  const int NP = NT >> 1;     // 8 pairs

  f32x4 acc[8][4];
  #pragma unroll
  for (int i=0;i<8;i++)
    #pragma unroll
    for (int j=0;j<4;j++) acc[i][j] = (f32x4){0.f,0.f,0.f,0.f};

  // Stage A-half X of tile kt: rows {g(2i+X)} = interleaved 64-row groups.
  #define STGA(kt_, X_) { \
    char* base_ = lds + ((kt_)&1)*32768; \
    _Pragma("unroll") \
    for (int l_=0;l_<2;l_++){ \
      const int slot_ = l_*512 + tid; \
      const int rp_ = slot_>>3; \
      const int row_ = ((rp_>>6)<<7) + (X_)*64 + (rp_&63); \
      const int blk_ = slot_&7; \
      const int sblk_ = blk_ ^ (row_&7); \
      async16(A + (size_t)(m0+row_)*K + ((kt_)<<6) + sblk_*8, base_ + (row_*8+blk_)*16); } }

  // Stage B-half X: interleaved 32-row groups.
  #define STGB(kt_, X_) { \
    char* base_ = lds + 65536 + ((kt_)&1)*32768; \
    _Pragma("unroll") \
    for (int l_=0;l_<2;l_++){ \
      const int slot_ = l_*512 + tid; \
      const int rp_ = slot_>>3; \
      const int row_ = ((rp_>>5)<<6) + (X_)*32 + (rp_&31); \
      const int blk_ = slot_&7; \
      const int sblk_ = blk_ ^ (row_&7); \
      async16(Bt + (size_t)(n0+row_)*K + ((kt_)<<6) + sblk_*8, base_ + (row_*8+blk_)*16); } }

  #define LDA(dst_, kt_, mh_) { \
    char* rdA_ = lds + ((kt_)&1)*32768; \
    _Pragma("unroll") \
    for (int mi_=0;mi_<4;mi_++){ \
      const int row_ = wr*128 + (mh_)*64 + mi_*16 + lane15; \
      _Pragma("unroll") \
      for (int ks_=0;ks_<2;ks_++){ \
        const int b_ = (ks_*4+lgrp) ^ (row_&7); \
        dst_[mi_][ks_] = *reinterpret_cast<const bf16x8*>(rdA_ + (row_*8 + b_)*16); } } }

  #define LDB(dst_, kt_, nh_) { \
    char* rdB_ = lds + 65536 + ((kt_)&1)*32768; \
    _Pragma("unroll") \
    for (int ni_=0;ni_<2;ni_++){ \
      const int row_ = wc*64 + (nh_)*32 + ni_*16 + lane15; \
      _Pragma("unroll") \
      for (int ks_=0;ks_<2;ks_++){ \
        const int b_ = (ks_*4+lgrp) ^ (row_&7); \
        dst_[ni_][ks_] = *reinterpret_cast<const bf16x8*>(rdB_ + (row_*8 + b_)*16); } } }

  #define PH_PRE() { __builtin_amdgcn_s_barrier(); \
    asm volatile("s_waitcnt lgkmcnt(0)" ::: "memory"); \
    __builtin_amdgcn_sched_barrier(0); }
  #define PH_POST() __builtin_amdgcn_s_barrier();

  #define MF(MB_, NB_, BF_) { __builtin_amdgcn_s_setprio(1); \
    _Pragma("unroll") \
    for (int mi_=0;mi_<4;mi_++) \
      _Pragma("unroll") \
      for (int ni_=0;ni_<2;ni_++) \
        _Pragma("unroll") \
        for (int ks_=0;ks_<2;ks_++) \
          acc[(MB_)+mi_][(NB_)+ni_] = __builtin_amdgcn_mfma_f32_16x16x32_bf16( \
              af[mi_][ks_], BF_[ni_][ks_], acc[(MB_)+mi_][(NB_)+ni_], 0, 0, 0); \
    __builtin_amdgcn_s_setprio(0); }

  // prologue: tile0 fully (4 halves), pace, then 3 halves of tile1
  STGA(0,0); STGB(0,0); STGA(0,1); STGB(0,1);
  asm volatile("s_waitcnt vmcnt(4)" ::: "memory");
  STGA(1,0); STGB(1,0); STGA(1,1);
  asm volatile("s_waitcnt vmcnt(6)" ::: "memory");
  __builtin_amdgcn_s_barrier();
  __builtin_amdgcn_sched_barrier(0);

  bf16x8 af[4][2], bf0[2][2], bf1[2][2];

  for (int j = 0; j < NP; ++j) {
    const int e = 2*j, o = 2*j+1;
    const bool nlast = (j+1 < NP);

    // ---- ph1: tile e, q(0,0) ----
    LDA(af, e, 0);
    LDB(bf0, e, 0);
    STGB(o, 1);
    PH_PRE(); MF(0, 0, bf0); PH_POST();
    // ---- ph2: q(0,1) ----
    LDB(bf1, e, 1);
    if (nlast) STGA(e+2, 0);
    PH_PRE(); MF(0, 2, bf1); PH_POST();
    // ---- ph3: q(1,1) ----
    LDA(af, e, 1);
    if (nlast) STGB(e+2, 0);
    PH_PRE(); MF(4, 2, bf1); PH_POST();
    // ---- ph4: q(1,0); counted wait publishes tile o ----
    if (nlast) STGA(e+2, 1);
    PH_PRE(); MF(4, 0, bf0);
    if (nlast) asm volatile("s_waitcnt vmcnt(6)" ::: "memory");
    else       asm volatile("s_waitcnt vmcnt(0)" ::: "memory");
    PH_POST();
    // ---- ph5: tile o, q(0,0) ----
    LDA(af, o, 0);
    LDB(bf0, o, 0);
    if (nlast) STGB(e+2, 1);
    PH_PRE(); MF(0, 0, bf0); PH_POST();
    // ---- ph6: q(0,1) ----
    LDB(bf1, o, 1);
    if (nlast) STGA(o+2, 0);
    PH_PRE(); MF(0, 2, bf1); PH_POST();
    // ---- ph7: q(1,1) ----
    LDA(af, o, 1);
    if (nlast) STGB(o+2, 0);
    PH_PRE(); MF(4, 2, bf1); PH_POST();
    // ---- ph8: q(1,0); counted wait publishes tile e+2 ----
    if (nlast) STGA(o+2, 1);
    PH_PRE(); MF(4, 0, bf0);
    if (nlast) asm volatile("s_waitcnt vmcnt(6)" ::: "memory");
    PH_POST();
  }
  #undef STGA
  #undef STGB
  #undef LDA
  #undef LDB
  #undef PH_PRE
  #undef PH_POST
  #undef MF

  #pragma unroll
  for (int ni = 0; ni < 4; ni++) {
    const int col = n0 + wc*64 + ni*16 + lane15;
    const float bv = bias ? bias[col] : 0.f;
    #pragma unroll
    for (int mi = 0; mi < 8; mi++) {
      #pragma unroll
      for (int r = 0; r < 4; r++) {
        const int row = m0 + wr*128 + mi*16 + lgrp*4 + r;
        float v = acc[mi][ni][r] + bv;
        if (EPI == 1) {
          Cout[(size_t)row*N + col] = (short)f2bf(gelu_f(v));
        } else {
          if (col < 3072)      Cout[(size_t)row*3072 + col] = (short)f2bf(v);
          else if (col < 3200) drive[(size_t)row*128 + (col-3072)] = v;
          else if (col < 4224) gate[(size_t)row*1024 + (col-3200)] = (short)f2bf(1.f/(1.f+__expf(-v)));
        }
      }
    }
  }
}

// ====== BM x 128 tile (BM=MT*32), BK=64, 4 waves, 2-buffer pipeline (R6) ====
// EPI 3 = RES: out = acc + bias + out  (fp32, in-place resid)
template<int MT, int EPI>
__global__ __launch_bounds__(256) void gemm128(
    const short* __restrict__ A, const short* __restrict__ Bt,
    const float* __restrict__ bias,
    void* __restrict__ Cout, int M, int N, int K)
{
  constexpr int BM  = MT * 32;
  constexpr int ABY = BM * 128;
  constexpr int STR = ABY + 16384;
  constexpr int MPQ = MT / 2;
  extern __shared__ char lds[];
  const int tid = threadIdx.x;
  const int ln = tid & 63, w = tid >> 6;
  const int wr = w >> 1, wc = w & 1;
  const int lane15 = ln & 15, lgrp = ln >> 4;

  const int gx = gridDim.x;
  const int nwg = gx * gridDim.y;
  int id = blockIdx.y * gx + blockIdx.x;
  if ((nwg & 7) == 0) { const int cpx = nwg >> 3; id = (id & 7) * cpx + (id >> 3); }
  const int m0 = (id / gx) * BM, n0 = (id % gx) * 128;

  const int NT = K >> 6;

  f32x4 acc[MT][4];
  #pragma unroll
  for (int i=0;i<MT;i++)
    #pragma unroll
    for (int j=0;j<4;j++) acc[i][j] = (f32x4){0.f,0.f,0.f,0.f};

  #define STG(k0_, bufA_, bufB_, p_) { \
    const int slot = (p_)*256 + tid; \
    const int row = slot >> 3, blk = slot & 7; \
    const int sblk = blk ^ (row & 7); \
    if ((p_) < MT) async16(A + (size_t)(m0+row)*K + (k0_) + sblk*8, (bufA_) + slot*16); \
    async16(Bt + (size_t)(n0+row)*K + (k0_) + sblk*8, (bufB_) + slot*16); }

  {
    char* bA = lds, *bB = lds + ABY;
    STG(0, bA, bB, 0); STG(0, bA, bB, 1); STG(0, bA, bB, 2); STG(0, bA, bB, 3);
    if (NT > 1) { char* cA = lds + STR, *cB = cA + ABY; STG(64, cA, cB, 0); }
    asm volatile("s_waitcnt vmcnt(0)" ::: "memory");
    __builtin_amdgcn_s_barrier();
    __builtin_amdgcn_sched_barrier(0);
  }

  for (int kt = 0; kt < NT; ++kt) {
    const int cur = kt & 1;
    char* rdA = lds + cur*STR;   char* rdB = rdA + ABY;
    char* wrA = lds + (cur^1)*STR; char* wrB = wrA + ABY;
    const int kn = (kt+1) << 6;
    bf16x8 bfr[4][2];
    #pragma unroll
    for (int ni = 0; ni < 4; ni++) {
      const int row = wc*64 + ni*16 + lane15;
      #pragma unroll
      for (int ks = 0; ks < 2; ks++) {
        const int b = (ks*4 + lgrp) ^ (row & 7);
        bfr[ni][ks] = *reinterpret_cast<const bf16x8*>(rdB + (row*8 + b)*16);
      }
    }
    if (kt+1 < NT) STG(kn, wrA, wrB, 1);
    #pragma unroll
    for (int mq = 0; mq < 2; ++mq) {
      bf16x8 af[MPQ][2];
      #pragma unroll
      for (int mi = 0; mi < MPQ; mi++) {
        const int row = wr*(MT*16) + (mq*MPQ+mi)*16 + lane15;
        #pragma unroll
        for (int ks = 0; ks < 2; ks++) {
          const int b = (ks*4 + lgrp) ^ (row & 7);
          af[mi][ks] = *reinterpret_cast<const bf16x8*>(rdA + (row*8 + b)*16);
        }
      }
      if (kt+1 < NT) STG(kn, wrA, wrB, 2+mq);
      __builtin_amdgcn_s_setprio(1);
      #pragma unroll
      for (int mi = 0; mi < MPQ; mi++)
        #pragma unroll
        for (int ni = 0; ni < 4; ni++)
          #pragma unroll
          for (int ks = 0; ks < 2; ks++)
            acc[mq*MPQ+mi][ni] = __builtin_amdgcn_mfma_f32_16x16x32_bf16(
                af[mi][ks], bfr[ni][ks], acc[mq*MPQ+mi][ni], 0, 0, 0);
      __builtin_amdgcn_s_setprio(0);
    }
    if (kt+1 < NT) {
      __builtin_amdgcn_s_barrier();
      if (kt+2 < NT) {
        STG((kt+2) << 6, rdA, rdB, 0);
        asm volatile("s_waitcnt vmcnt(2)" ::: "memory");
      } else {
        asm volatile("s_waitcnt vmcnt(0)" ::: "memory");
      }
      __builtin_amdgcn_s_barrier();
      __builtin_amdgcn_sched_barrier(0);
    }
  }
  #undef STG

  #pragma unroll
  for (int ni = 0; ni < 4; ni++) {
    const int col = n0 + wc*64 + ni*16 + lane15;
    const float bv = bias ? bias[col] : 0.f;
    #pragma unroll
    for (int mi = 0; mi < MT; mi++) {
      #pragma unroll
      for (int r = 0; r < 4; r++) {
        const int row = m0 + wr*(MT*16) + mi*16 + lgrp*4 + r;
        const float v = acc[mi][ni][r] + bv;
        float* o = (float*)Cout;
        o[(size_t)row*N + col] = v + o[(size_t)row*N + col];
      }
    }
  }
}

// ====== Fused W_O + C_w combine: out = x + g*(attn@WO+bO) + (1-g)*(st@Cw) ===
__global__ __launch_bounds__(256) void wo_comb(
    const short* __restrict__ A1, const short* __restrict__ B1t,   // attn, wT_o
    const short* __restrict__ A2, const short* __restrict__ B2t,   // st, wT_c
    const float* __restrict__ bias, const float* __restrict__ e_x,
    const short* __restrict__ e_g, float* __restrict__ Cout)
{
  constexpr int ABY = 8192;
  constexpr int STR = ABY + 16384;
  extern __shared__ char lds[];
  const int tid = threadIdx.x;
  const int ln = tid & 63, w = tid >> 6;
  const int wr = w >> 1, wc = w & 1;
  const int lane15 = ln & 15, lgrp = ln >> 4;
  const int K = 1024, N = 1024;

  const int gx = gridDim.x;
  const int nwg = gx * gridDim.y;
  int id = blockIdx.y * gx + blockIdx.x;
  if ((nwg & 7) == 0) { const int cpx = nwg >> 3; id = (id & 7) * cpx + (id >> 3); }
  const int m0 = (id / gx) * 64, n0 = (id % gx) * 128;

  f32x4 acc1[2][4], acc2[2][4];
  #pragma unroll
  for (int i=0;i<2;i++)
    #pragma unroll
    for (int j=0;j<4;j++){ acc1[i][j] = (f32x4){0.f,0.f,0.f,0.f}; acc2[i][j] = (f32x4){0.f,0.f,0.f,0.f}; }

  #define STGW(Asrc_, Bsrc_, AK_, k0_, bufA_, bufB_, p_) { \
    const int slot = (p_)*256 + tid; \
    const int row = slot >> 3, blk = slot & 7; \
    const int sblk = blk ^ (row & 7); \
    if ((p_) < 2) async16(Asrc_ + (size_t)(m0+row)*(AK_) + (k0_) + sblk*8, (bufA_) + slot*16); \
    async16(Bsrc_ + (size_t)(n0+row)*(AK_) + (k0_) + sblk*8, (bufB_) + slot*16); }

  {
    char* bA = lds, *bB = lds + ABY;
    STGW(A1, B1t, K, 0, bA, bB, 0); STGW(A1, B1t, K, 0, bA, bB, 1);
    STGW(A1, B1t, K, 0, bA, bB, 2); STGW(A1, B1t, K, 0, bA, bB, 3);
    { char* cA = lds + STR, *cB = cA + ABY; STGW(A1, B1t, K, 64, cA, cB, 0); }
    asm volatile("s_waitcnt vmcnt(0)" ::: "memory");
    __builtin_amdgcn_s_barrier();
    __builtin_amdgcn_sched_barrier(0);
  }

  const int NT = 16;
  for (int kt = 0; kt < NT; ++kt) {
    const int cur = kt & 1;
    char* rdA = lds + cur*STR;   char* rdB = rdA + ABY;
    char* wrA = lds + (cur^1)*STR; char* wrB = wrA + ABY;
    const int kn = (kt+1) << 6;
    bf16x8 bfr[4][2];
    #pragma unroll
    for (int ni = 0; ni < 4; ni++) {
      const int row = wc*64 + ni*16 + lane15;
      #pragma unroll
      for (int ks = 0; ks < 2; ks++) {
        const int b = (ks*4 + lgrp) ^ (row & 7);
        bfr[ni][ks] = *reinterpret_cast<const bf16x8*>(rdB + (row*8 + b)*16);
      }
    }
    if (kt+1 < NT) STGW(A1, B1t, K, kn, wrA, wrB, 1);
    #pragma unroll
    for (int mq = 0; mq < 2; ++mq) {
      bf16x8 af[2];
      {
        const int row = wr*32 + mq*16 + lane15;
        #pragma unroll
        for (int ks = 0; ks < 2; ks++) {
          const int b = (ks*4 + lgrp) ^ (row & 7);
          af[ks] = *reinterpret_cast<const bf16x8*>(rdA + (row*8 + b)*16);
        }
      }
      if (kt+1 < NT) STGW(A1, B1t, K, kn, wrA, wrB, 2+mq);
      __builtin_amdgcn_s_setprio(1);
      #pragma unroll
      for (int ni = 0; ni < 4; ni++)
        #pragma unroll
        for (int ks = 0; ks < 2; ks++)
          acc1[mq][ni] = __builtin_amdgcn_mfma_f32_16x16x32_bf16(
              af[ks], bfr[ni][ks], acc1[mq][ni], 0, 0, 0);
      __builtin_amdgcn_s_setprio(0);
    }
    if (kt+1 < NT) {
      __builtin_amdgcn_s_barrier();
      if (kt+2 < NT) {
        STGW(A1, B1t, K, (kt+2) << 6, rdA, rdB, 0);
        asm volatile("s_waitcnt vmcnt(2)" ::: "memory");
      } else {
        asm volatile("s_waitcnt vmcnt(0)" ::: "memory");
      }
      __builtin_amdgcn_s_barrier();
      __builtin_amdgcn_sched_barrier(0);
    }
  }

  // ---- phase 2: acc2 = st @ Cw (K2 = 128, two 64-K tiles, no pipeline) ----
  __builtin_amdgcn_s_barrier();
  {
    char* bA0 = lds,       *bB0 = lds + ABY;
    char* bA1 = lds + STR, *bB1 = bA1 + ABY;
    STGW(A2, B2t, 128, 0,  bA0, bB0, 0); STGW(A2, B2t, 128, 0,  bA0, bB0, 1);
    STGW(A2, B2t, 128, 0,  bA0, bB0, 2); STGW(A2, B2t, 128, 0,  bA0, bB0, 3);
    STGW(A2, B2t, 128, 64, bA1, bB1, 0); STGW(A2, B2t, 128, 64, bA1, bB1, 1);
    STGW(A2, B2t, 128, 64, bA1, bB1, 2); STGW(A2, B2t, 128, 64, bA1, bB1, 3);
    asm volatile("s_waitcnt vmcnt(0)" ::: "memory");
    __builtin_amdgcn_s_barrier();
  }
  #pragma unroll
  for (int t2 = 0; t2 < 2; ++t2) {
    char* rdA = lds + t2*STR; char* rdB = rdA + ABY;
    bf16x8 bfr2[4][2];
    #pragma unroll
    for (int ni = 0; ni < 4; ni++) {
      const int brow = wc*64 + ni*16 + lane15;
      #pragma unroll
      for (int ks = 0; ks < 2; ks++) {
        const int b = (ks*4 + lgrp) ^ (brow & 7);
        bfr2[ni][ks] = *reinterpret_cast<const bf16x8*>(rdB + (brow*8 + b)*16);
      }
    }
    #pragma unroll
    for (int mi = 0; mi < 2; mi++) {
      bf16x8 af[2];
      const int row = wr*32 + mi*16 + lane15;
      #pragma unroll
      for (int ks = 0; ks < 2; ks++) {
        const int b = (ks*4 + lgrp) ^ (row & 7);
        af[ks] = *reinterpret_cast<const bf16x8*>(rdA + (row*8 + b)*16);
      }
      #pragma unroll
      for (int ni = 0; ni < 4; ni++)
        #pragma unroll
        for (int ks = 0; ks < 2; ks++)
          acc2[mi][ni] = __builtin_amdgcn_mfma_f32_16x16x32_bf16(af[ks], bfr2[ni][ks], acc2[mi][ni], 0, 0, 0);
    }
  }
  #undef STGW

  #pragma unroll
  for (int ni = 0; ni < 4; ni++) {
    const int col = n0 + wc*64 + ni*16 + lane15;
    const float bv = bias[col];
    #pragma unroll
    for (int mi = 0; mi < 2; mi++) {
      #pragma unroll
      for (int r = 0; r < 4; r++) {
        const int row = m0 + wr*32 + mi*16 + lgrp*4 + r;
        const float g = bf2f(e_g[(size_t)row*1024 + col]);
        Cout[(size_t)row*N + col] = e_x[(size_t)row*1024 + col]
            + g*(acc1[mi][ni][r] + bv) + (1.f-g)*acc2[mi][ni][r];
      }
    }
  }
}

// ---------------- Flash sliding-window attention (MFMA, bf16) ---------------
#define ATS 72
__global__ __launch_bounds__(256) void attn_mfma(const short* __restrict__ qkv,
                                                 short* __restrict__ attn_out)
{
  __shared__ short Qs[64*ATS];
  __shared__ short Ks[64*ATS];
  __shared__ short Vt[64*ATS];
  __shared__ short Ps[4][16*ATS];
  const int tid = threadIdx.x;
  const int ln = tid & 63, w = tid >> 6;
  const int qt0 = (blockIdx.x >> 4) * 64;
  const int h = blockIdx.x & 15;

  {
    const int jr = tid >> 3, d0 = (tid & 7) * 8;
    #pragma unroll
    for (int p = 0; p < 2; p++) {
      const int j = jr + p*32;
      const bf16x8 v = *reinterpret_cast<const bf16x8*>(&qkv[(size_t)(qt0 + j)*3072 + h*64 + d0]);
      const int blk = (d0 >> 3) ^ (j & 7);
      *reinterpret_cast<bf16x8*>(&Qs[j*ATS + blk*8]) = v;
    }
  }

  float mrow[4], lrow[4];
  f32x4 oacc[4];
  #pragma unroll
  for (int r=0;r<4;r++){ mrow[r] = -1e30f; lrow[r] = 0.f; }
  #pragma unroll
  for (int df=0;df<4;df++) oacc[df] = (f32x4){0.f,0.f,0.f,0.f};

  const int qrow_lane = w*16 + (ln>>4)*4;
  const int qtile = qt0 >> 6;
  const int cstart = (qtile >= 4) ? 0 : (4 - qtile);

  for (int c = cstart; c < 5; c++) {
    const int cs = qt0 - 256 + c*64;
    {
      const int jr = tid >> 3, d0 = (tid & 7) * 8;
      #pragma unroll
      for (int p = 0; p < 2; p++) {
        const int j = jr + p*32;
        const size_t krow = (size_t)(cs + j)*3072 + h*64;
        const bf16x8 kv = *reinterpret_cast<const bf16x8*>(&qkv[krow + 1024 + d0]);
        const int blk = (d0>>3) ^ (j & 7);
        *reinterpret_cast<bf16x8*>(&Ks[j*ATS + blk*8]) = kv;
        const bf16x8 vv = *reinterpret_cast<const bf16x8*>(&qkv[krow + 2048 + d0]);
        #pragma unroll
        for (int i = 0; i < 8; i++) {
          const int d = d0 + i;
          const int jb = (j >> 3) ^ ((d >> 3) & 7);
          Vt[d*ATS + jb*8 + (j & 7)] = ((const short*)&vv)[i];
        }
      }
    }
    __syncthreads();

    bf16x8 aq[2];
    #pragma unroll
    for (int ks=0; ks<2; ks++){
      const int row = w*16 + (ln & 15);
      const int b = (ks*4 + (ln>>4)) ^ (row & 7);
      aq[ks] = *reinterpret_cast<const bf16x8*>(&Qs[row*ATS + b*8]);
    }
    float sv[4][4];
    #pragma unroll
    for (int nf=0; nf<4; nf++){
      const int krow = nf*16 + (ln & 15);
      f32x4 s = (f32x4){0.f,0.f,0.f,0.f};
      #pragma unroll
      for (int ks=0; ks<2; ks++){
        const int b = (ks*4 + (ln>>4)) ^ (krow & 7);
        const bf16x8 bk = *reinterpret_cast<const bf16x8*>(&Ks[krow*ATS + b*8]);
        s = __builtin_amdgcn_mfma_f32_16x16x32_bf16(aq[ks], bk, s, 0, 0, 0);
      }
      const int k_abs = cs + nf*16 + (ln & 15);
      #pragma unroll
      for (int r=0;r<4;r++){
        const int t_abs = qt0 + qrow_lane + r;
        const bool valid = (k_abs <= t_abs) && (k_abs >= t_abs - 255);
        sv[nf][r] = valid ? s[r]*0.125f : -1e30f;
      }
    }
    float cm[4], alpha[4], rs[4];
    #pragma unroll
    for (int r=0;r<4;r++){
      cm[r] = fmaxf(fmaxf(sv[0][r],sv[1][r]), fmaxf(sv[2][r],sv[3][r]));
      #pragma unroll
      for (int off=1; off<16; off<<=1) cm[r] = fmaxf(cm[r], __shfl_xor(cm[r], off));
      const float mnew = fmaxf(mrow[r], cm[r]);
      alpha[r] = __expf(mrow[r] - mnew);
      mrow[r] = mnew;
      rs[r] = 0.f;
    }
    #pragma unroll
    for (int nf=0; nf<4; nf++){
      const int pcol = nf*16 + (ln & 15);
      #pragma unroll
      for (int r=0;r<4;r++){
        const float p = (sv[nf][r] <= -1e29f) ? 0.f : __expf(sv[nf][r] - mrow[r]);
        rs[r] += p;
        const int prow = (ln>>4)*4 + r;
        const int pb = (pcol>>3) ^ (prow & 7);
        Ps[w][prow*ATS + pb*8 + (pcol & 7)] = (short)f2bf(p);
      }
    }
    #pragma unroll
    for (int r=0;r<4;r++){
      #pragma unroll
      for (int off=1; off<16; off<<=1) rs[r] += __shfl_xor(rs[r], off);
      lrow[r] = lrow[r]*alpha[r] + rs[r];
      #pragma unroll
      for (int df=0; df<4; df++) oacc[df][r] *= alpha[r];
    }
    bf16x8 ap[2];
    #pragma unroll
    for (int ks=0; ks<2; ks++){
      const int prow = (ln & 15);
      const int b = (ks*4 + (ln>>4)) ^ (prow & 7);
      ap[ks] = *reinterpret_cast<const bf16x8*>(&Ps[w][prow*ATS + b*8]);
    }
    #pragma unroll
    for (int df=0; df<4; df++){
      const int vrow = df*16 + (ln & 15);
      #pragma unroll
      for (int ks=0; ks<2; ks++){
        const int b = (ks*4 + (ln>>4)) ^ ((vrow>>3) & 7);
        const bf16x8 bv = *reinterpret_cast<const bf16x8*>(&Vt[vrow*ATS + b*8]);
        oacc[df] = __builtin_amdgcn_mfma_f32_16x16x32_bf16(ap[ks], bv, oacc[df], 0, 0, 0);
      }
    }
    __syncthreads();
  }

  #pragma unroll
  for (int df=0; df<4; df++)
    #pragma unroll
    for (int r=0; r<4; r++){
      const int t = qt0 + qrow_lane + r;
      const int d = df*16 + (ln & 15);
      attn_out[(size_t)t*1024 + h*64 + d] = (short)f2bf(oacc[df][r] / lrow[r]);
    }
}

// ---------------- SSM scan as 16-tap convolution (compact drive) ------------
__global__ __launch_bounds__(256) void scan_kernel(const float* __restrict__ drive,
    const float* __restrict__ Aa, short* __restrict__ states)
{
  const int idx = blockIdx.x*256 + threadIdx.x;
  const int t = idx >> 7, s = idx & 127;
  const float a = Aa[s];
  float acc = 0.f, pw = 1.f;
  const int kmax = (t+1 < 16) ? (t+1) : 16;
  for (int k=0;k<kmax;k++){
    acc = fmaf(pw, drive[(size_t)(t-k)*128 + s], acc);
    pw *= a;
  }
  states[idx] = (short)f2bf(acc);
}

extern "C" void kernel_launch(void* const* d_in, const int* in_sizes, int n_in,
                              void* d_out, int out_size, void* d_ws, size_t ws_size,
                              hipStream_t stream)
{
  const float* x     = (const float*)d_in[0];
  const float* ln1_g = (const float*)d_in[1];
  const float* ln1_b = (const float*)d_in[2];
  const float* ln2_g = (const float*)d_in[3];
  const float* ln2_b = (const float*)d_in[4];
  const float* W_qkv = (const float*)d_in[5];
  const float* W_O   = (const float*)d_in[6];
  const float* b_O   = (const float*)d_in[7];
  const float* W_ug  = (const float*)d_in[8];
  const float* b_ug  = (const float*)d_in[9];
  const float* B_w   = (const float*)d_in[10];
  const float* A     = (const float*)d_in[11];
  const float* C_w   = (const float*)d_in[12];
  const float* W1    = (const float*)d_in[13];
  const float* b1    = (const float*)d_in[14];
  const float* W2    = (const float*)d_in[15];
  const float* b2    = (const float*)d_in[16];
  float* out = (float*)d_out;
  char* ws = (char*)d_ws;

  short* qkv_bf = (short*)(ws + 0);          // 24MB
  short* attn_bf= (short*)(ws + 25165824);   // 8MB
  short* xn_bf  = (short*)(ws + 33554432);   // 8MB (h aliases)
  short* g_bf   = (short*)(ws + 41943040);   // 8MB  gate (sigmoid, bf16)
  float* drive  = (float*)(ws + 50331648);   // 2MB  fp32 [4096][128]
  short* st_bf  = (short*)(ws + 52428800);   // 1MB
  float* b_all  = (float*)(ws + 53477376);   // 64KB reserve
  short* wT_all = (short*)(ws + 53542912);   // [4352][1024] 9MB reserve
  short* wT_o   = (short*)(ws + 62980096);   // 2MB
  short* wT_c   = (short*)(ws + 65077248);   // 0.25MB
  short* wT_1   = (short*)(ws + 65339392);   // 8MB
  short* wT_2   = (short*)(ws + 73728000);   // 8MB
  short* mid_bf = (short*)(ws + 0);          // 32MB alias (dead qkv+attn)
  short* h_bf   = xn_bf;

  static bool attr_done = false;
  if (!attr_done) {
    hipFuncSetAttribute((const void*)gemm256<1>, hipFuncAttributeMaxDynamicSharedMemorySize, 131072);
    hipFuncSetAttribute((const void*)gemm256<2>, hipFuncAttributeMaxDynamicSharedMemorySize, 131072);
    hipFuncSetAttribute((const void*)(gemm128<2,3>), hipFuncAttributeMaxDynamicSharedMemorySize, 49152);
    hipFuncSetAttribute((const void*)wo_comb, hipFuncAttributeMaxDynamicSharedMemorySize, 49152);
    attr_done = true;
  }

  // weights: fused [4352][1024] = qkv^T | ug^T(+B_w) | zero pad
  conv_transpose<<<dim3(96,32),  256, 0, stream>>>(W_qkv, wT_all, 1024, 3072, nullptr, 0);
  conv_transpose<<<dim3(36,32),  256, 0, stream>>>(W_ug,  wT_all + (size_t)3072*1024, 1024, 1152, B_w, 128);
  hipMemsetAsync(wT_all + (size_t)4224*1024, 0, (size_t)128*1024*2, stream);
  init_ball<<<17, 256, 0, stream>>>(b_ug, b_all);
  conv_transpose<<<dim3(32,32),  256, 0, stream>>>(W_O,   wT_o,   1024, 1024, nullptr, 0);
  conv_transpose<<<dim3(32,4),   256, 0, stream>>>(C_w,   wT_c,   128,  1024, nullptr, 0);
  conv_transpose<<<dim3(128,32), 256, 0, stream>>>(W1,    wT_1,   1024, 4096, nullptr, 0);
  conv_transpose<<<dim3(32,128), 256, 0, stream>>>(W2,    wT_2,   4096, 1024, nullptr, 0);

  ln_bf16<<<4096, 256, 0, stream>>>(x, ln1_g, ln1_b, xn_bf);
  gemm256<2><<<dim3(17,16), 512, 131072, stream>>>(xn_bf, wT_all, b_all, qkv_bf, drive, g_bf, 4096, 4352, 1024);
  attn_mfma<<<1024, 256, 0, stream>>>(qkv_bf, attn_bf);
  scan_kernel<<<2048, 256, 0, stream>>>(drive, A, st_bf);
  wo_comb<<<dim3(8,64), 256, 49152, stream>>>(attn_bf, wT_o, st_bf, wT_c, b_O, x, g_bf, out);
  ln_bf16<<<4096, 256, 0, stream>>>(out, ln2_g, ln2_b, h_bf);
  gemm256<1><<<dim3(16,16), 512, 131072, stream>>>(h_bf, wT_1, b1, mid_bf, nullptr, nullptr, 4096, 4096, 1024);
  gemm128<2,3><<<dim3(8,64), 256, 49152, stream>>>(mid_bf, wT_2, b2, out, 4096, 1024, 4096);
}

// Round 11
// 239.395 us; speedup vs baseline: 1.2008x; 1.1867x over previous
//
#include <hip/hip_runtime.h>
#include <hip/hip_bf16.h>
#include <math.h>

typedef short bf16x8 __attribute__((ext_vector_type(8)));
typedef float f32x4  __attribute__((ext_vector_type(4)));

#define GLOBAL_AS __attribute__((address_space(1)))
#define LDS_AS    __attribute__((address_space(3)))

__device__ __forceinline__ void async16(const void* g, void* l) {
  __builtin_amdgcn_global_load_lds((GLOBAL_AS void*)(g), (LDS_AS void*)(l), 16, 0, 0);
}

__device__ __forceinline__ unsigned short f2bf(float f){
  union { float f; unsigned u; } x; x.f = f;
  return (unsigned short)((x.u + 0x7fffu + ((x.u >> 16) & 1u)) >> 16);
}
__device__ __forceinline__ float bf2f(short s){
  union { unsigned u; float f; } x; x.u = ((unsigned)(unsigned short)s) << 16;
  return x.f;
}
__device__ __forceinline__ float gelu_f(float x){
  return 0.5f*x*(1.f+erff(x*0.70710678118654752f));
}

// ---------------- LayerNorm -> bf16 out ------------------------------------
__global__ __launch_bounds__(256) void ln_bf16(const float* __restrict__ in,
    const float* __restrict__ gg, const float* __restrict__ bb, short* __restrict__ out)
{
  const int row = blockIdx.x;
  const int tid = threadIdx.x;
  const float4 v = reinterpret_cast<const float4*>(in + (size_t)row*1024)[tid];
  float s  = v.x+v.y+v.z+v.w;
  float sq = v.x*v.x+v.y*v.y+v.z*v.z+v.w*v.w;
  #pragma unroll
  for (int off=32; off; off>>=1){ s += __shfl_xor(s,off); sq += __shfl_xor(sq,off); }
  __shared__ float ss[4], qs[4];
  const int wid = tid>>6, lane = tid&63;
  if (lane==0){ ss[wid]=s; qs[wid]=sq; }
  __syncthreads();
  s  = ss[0]+ss[1]+ss[2]+ss[3];
  sq = qs[0]+qs[1]+qs[2]+qs[3];
  const float mu  = s * (1.f/1024.f);
  const float var = sq*(1.f/1024.f) - mu*mu;
  const float rs  = rsqrtf(var + 1e-5f);
  const float4 g4 = reinterpret_cast<const float4*>(gg)[tid];
  const float4 b4 = reinterpret_cast<const float4*>(bb)[tid];
  ushort4 o;
  o.x = f2bf((v.x-mu)*rs*g4.x+b4.x);
  o.y = f2bf((v.y-mu)*rs*g4.y+b4.y);
  o.z = f2bf((v.z-mu)*rs*g4.z+b4.z);
  o.w = f2bf((v.w-mu)*rs*g4.w+b4.w);
  *reinterpret_cast<ushort4*>(out + (size_t)row*1024 + tid*4) = o;
}

// ------------- fused weight prep: all transposes + bias vector in 1 launch --
__device__ __forceinline__ void conv_body(const float* __restrict__ in,
    short* __restrict__ out, int K, int N, const float* __restrict__ add, int addN,
    int bx, int by)
{
  __shared__ float tile[32][33];
  const int n0 = bx*32, k0 = by*32;
  const int r = threadIdx.x >> 3, c4 = (threadIdx.x & 7)*4;
  float4 v = *reinterpret_cast<const float4*>(&in[(size_t)(k0+r)*N + n0 + c4]);
  if (add && (n0 + c4) < addN) {
    const float* ap = &add[(size_t)(k0+r)*addN + n0 + c4];
    v.x += ap[0]; v.y += ap[1]; v.z += ap[2]; v.w += ap[3];
  }
  tile[r][c4+0]=v.x; tile[r][c4+1]=v.y; tile[r][c4+2]=v.z; tile[r][c4+3]=v.w;
  __syncthreads();
  ushort4 o;
  o.x = f2bf(tile[c4+0][r]); o.y = f2bf(tile[c4+1][r]);
  o.z = f2bf(tile[c4+2][r]); o.w = f2bf(tile[c4+3][r]);
  *reinterpret_cast<ushort4*>(&out[(size_t)(n0+r)*K + k0 + c4]) = o;
}

__global__ __launch_bounds__(256) void prep_weights(
    const float* __restrict__ W_qkv, const float* __restrict__ W_O,
    const float* __restrict__ W_ug,  const float* __restrict__ B_w,
    const float* __restrict__ C_w,   const float* __restrict__ W1,
    const float* __restrict__ W2,    const float* __restrict__ b_ug,
    short* __restrict__ wT_qkv, short* __restrict__ wT_o,
    short* __restrict__ wT_ug,  short* __restrict__ wT_c,
    short* __restrict__ wT_1,   short* __restrict__ wT_2,
    float* __restrict__ b_all)
{
  const int bid = blockIdx.x;
  if (bid < 3072) {                       // W_qkv [1024][3072] -> [3072][1024], 96x32
    conv_body(W_qkv, wT_qkv, 1024, 3072, nullptr, 0, bid % 96, bid / 96);
  } else if (bid < 4224) {                // W_ug (+B_w) [1024][1152] -> [1152][1024], 36x32
    const int j = bid - 3072;
    conv_body(W_ug, wT_ug, 1024, 1152, B_w, 128, j % 36, j / 36);
  } else if (bid < 5248) {                // W_O [1024][1024], 32x32
    const int j = bid - 4224;
    conv_body(W_O, wT_o, 1024, 1024, nullptr, 0, j % 32, j / 32);
  } else if (bid < 5376) {                // C_w [128][1024] -> [1024][128], 32x4
    const int j = bid - 5248;
    conv_body(C_w, wT_c, 128, 1024, nullptr, 0, j % 32, j / 32);
  } else if (bid < 9472) {                // W1 [1024][4096] -> [4096][1024], 128x32
    const int j = bid - 5376;
    conv_body(W1, wT_1, 1024, 4096, nullptr, 0, j % 128, j / 128);
  } else if (bid < 13568) {               // W2 [4096][1024] -> [1024][4096], 32x128
    const int j = bid - 9472;
    conv_body(W2, wT_2, 4096, 1024, nullptr, 0, j % 32, j / 32);
  } else {                                // b_all (17 blocks x 256 = 4352)
    const int i = (bid - 13568)*256 + threadIdx.x;
    float v = 0.f;
    if (i >= 3072 && i < 4224) v = b_ug[i-3072];
    b_all[i] = v;   // b_all unused by ug path here but kept for layout parity
  }
}

// ============ 256x256 tile, BK=64, 8 waves, counted-vmcnt pipeline ==========
// EPI: 0 = plain -> bf16 out, 1 = bias+gelu -> bf16 out.
template<int EPI>
__global__ __launch_bounds__(512) void gemm256(
    const short* __restrict__ A, const short* __restrict__ Bt,
    const float* __restrict__ bias, short* __restrict__ Cout,
    int M, int N, int K)
{
  extern __shared__ char lds[];     // 2 bufs x (A 32KB + B 32KB) = 128KB
  const int tid = threadIdx.x;
  const int ln = tid & 63, w = tid >> 6;
  const int wr = w >> 2, wc = w & 3;          // 2 x 4 wave grid
  const int lane15 = ln & 15, lgrp = ln >> 4;

  const int gx = gridDim.x;
  const int nwg = gx * gridDim.y;
  int id = blockIdx.y * gx + blockIdx.x;
  if ((nwg & 7) == 0) { const int cpx = nwg >> 3; id = (id & 7) * cpx + (id >> 3); }
  const int m0 = (id / gx) * 256, n0 = (id % gx) * 256;

  const int NT = K >> 6;

  f32x4 acc[8][4];
  #pragma unroll
  for (int i=0;i<8;i++)
    #pragma unroll
    for (int j=0;j<4;j++) acc[i][j] = (f32x4){0.f,0.f,0.f,0.f};

  #define STG256(k0_, bufA_, bufB_, p_) { \
    const int slot = (p_)*512 + tid; \
    const int row = slot >> 3, blk = slot & 7; \
    const int sblk = blk ^ (row & 7); \
    async16(A  + (size_t)(m0+row)*K + (k0_) + sblk*8, (bufA_) + slot*16); \
    async16(Bt + (size_t)(n0+row)*K + (k0_) + sblk*8, (bufB_) + slot*16); }

  {
    char* bA = lds, *bB = lds + 32768;
    STG256(0, bA, bB, 0); STG256(0, bA, bB, 1); STG256(0, bA, bB, 2); STG256(0, bA, bB, 3);
    if (NT > 1) { char* cA = lds + 65536, *cB = cA + 32768; STG256(64, cA, cB, 0); }
    asm volatile("s_waitcnt vmcnt(0)" ::: "memory");
    __builtin_amdgcn_s_barrier();
    __builtin_amdgcn_sched_barrier(0);
  }

  for (int kt = 0; kt < NT; ++kt) {
    const int cur = kt & 1;
    char* rdA = lds + cur*65536;  char* rdB = rdA + 32768;
    char* wrA = lds + (cur^1)*65536; char* wrB = wrA + 32768;
    const int kn = (kt+1) << 6;
    // ---- B fragments once per tile (8 ds_read_b128) ----
    bf16x8 bfr[4][2];
    #pragma unroll
    for (int ni = 0; ni < 4; ni++) {
      const int row = wc*64 + ni*16 + lane15;
      #pragma unroll
      for (int ks = 0; ks < 2; ks++) {
        const int b = (ks*4 + lgrp) ^ (row & 7);
        bfr[ni][ks] = *reinterpret_cast<const bf16x8*>(rdB + (row*8 + b)*16);
      }
    }
    if (kt+1 < NT) STG256(kn, wrA, wrB, 1);
    // ---- two m-halves: A fragments once each (8 reads), 32 MFMA ----
    #pragma unroll
    for (int mq = 0; mq < 2; ++mq) {
      bf16x8 af[4][2];
      #pragma unroll
      for (int mi = 0; mi < 4; mi++) {
        const int row = wr*128 + (mq*4+mi)*16 + lane15;
        #pragma unroll
        for (int ks = 0; ks < 2; ks++) {
          const int b = (ks*4 + lgrp) ^ (row & 7);
          af[mi][ks] = *reinterpret_cast<const bf16x8*>(rdA + (row*8 + b)*16);
        }
      }
      if (kt+1 < NT) STG256(kn, wrA, wrB, 2+mq);
      #pragma unroll
      for (int mi = 0; mi < 4; mi++)
        #pragma unroll
        for (int ni = 0; ni < 4; ni++)
          #pragma unroll
          for (int ks = 0; ks < 2; ks++)
            acc[mq*4+mi][ni] = __builtin_amdgcn_mfma_f32_16x16x32_bf16(
                af[mi][ks], bfr[ni][ks], acc[mq*4+mi][ni], 0, 0, 0);
    }
    if (kt+1 < NT) {
      __builtin_amdgcn_s_barrier();
      if (kt+2 < NT) {
        STG256((kt+2) << 6, rdA, rdB, 0);
        asm volatile("s_waitcnt vmcnt(2)" ::: "memory");
      } else {
        asm volatile("s_waitcnt vmcnt(0)" ::: "memory");
      }
      __builtin_amdgcn_s_barrier();
      __builtin_amdgcn_sched_barrier(0);
    }
  }
  #undef STG256

  #pragma unroll
  for (int ni = 0; ni < 4; ni++) {
    const int col = n0 + wc*64 + ni*16 + lane15;
    const float bv = bias ? bias[col] : 0.f;
    #pragma unroll
    for (int mi = 0; mi < 8; mi++) {
      #pragma unroll
      for (int r = 0; r < 4; r++) {
        const int row = m0 + wr*128 + mi*16 + lgrp*4 + r;
        float v = acc[mi][ni][r] + bv;
        if (EPI == 1) v = gelu_f(v);
        Cout[(size_t)row*N + col] = (short)f2bf(v);
      }
    }
  }
}

// ====== BM x 128 tile (BM = MT*32), BK=64, 4 waves, counted-vmcnt pipeline ==
// EPI: 1 = UG split: col<128 -> drive fp32[.][128]; col>=128 -> sigmoid bf16 gate
//      3 = RES: out = acc + bias + out  (fp32, in-place resid)
template<int MT, int EPI>
__global__ __launch_bounds__(256) void gemm128(
    const short* __restrict__ A, const short* __restrict__ Bt,
    const float* __restrict__ bias,
    const short* __restrict__ e_g,
    void* __restrict__ Cout, int M, int N, int K)
{
  constexpr int BM  = MT * 32;
  constexpr int ABY = BM * 128;         // A buf bytes
  constexpr int STR = ABY + 16384;
  constexpr int MPQ = MT / 2;
  extern __shared__ char lds[];
  const int tid = threadIdx.x;
  const int ln = tid & 63, w = tid >> 6;
  const int wr = w >> 1, wc = w & 1;
  const int lane15 = ln & 15, lgrp = ln >> 4;

  const int gx = gridDim.x;
  const int nwg = gx * gridDim.y;
  int id = blockIdx.y * gx + blockIdx.x;
  if ((nwg & 7) == 0) { const int cpx = nwg >> 3; id = (id & 7) * cpx + (id >> 3); }
  const int m0 = (id / gx) * BM, n0 = (id % gx) * 128;

  const int NT = K >> 6;

  f32x4 acc[MT][4];
  #pragma unroll
  for (int i=0;i<MT;i++)
    #pragma unroll
    for (int j=0;j<4;j++) acc[i][j] = (f32x4){0.f,0.f,0.f,0.f};

  #define STG(k0_, bufA_, bufB_, p_) { \
    const int slot = (p_)*256 + tid; \
    const int row = slot >> 3, blk = slot & 7; \
    const int sblk = blk ^ (row & 7); \
    if ((p_) < MT) async16(A + (size_t)(m0+row)*K + (k0_) + sblk*8, (bufA_) + slot*16); \
    async16(Bt + (size_t)(n0+row)*K + (k0_) + sblk*8, (bufB_) + slot*16); }

  {
    char* bA = lds, *bB = lds + ABY;
    STG(0, bA, bB, 0); STG(0, bA, bB, 1); STG(0, bA, bB, 2); STG(0, bA, bB, 3);
    if (NT > 1) { char* cA = lds + STR, *cB = cA + ABY; STG(64, cA, cB, 0); }
    asm volatile("s_waitcnt vmcnt(0)" ::: "memory");
    __builtin_amdgcn_s_barrier();
    __builtin_amdgcn_sched_barrier(0);
  }

  for (int kt = 0; kt < NT; ++kt) {
    const int cur = kt & 1;
    char* rdA = lds + cur*STR;   char* rdB = rdA + ABY;
    char* wrA = lds + (cur^1)*STR; char* wrB = wrA + ABY;
    const int kn = (kt+1) << 6;
    bf16x8 bfr[4][2];
    #pragma unroll
    for (int ni = 0; ni < 4; ni++) {
      const int row = wc*64 + ni*16 + lane15;
      #pragma unroll
      for (int ks = 0; ks < 2; ks++) {
        const int b = (ks*4 + lgrp) ^ (row & 7);
        bfr[ni][ks] = *reinterpret_cast<const bf16x8*>(rdB + (row*8 + b)*16);
      }
    }
    if (kt+1 < NT) STG(kn, wrA, wrB, 1);
    #pragma unroll
    for (int mq = 0; mq < 2; ++mq) {
      bf16x8 af[MPQ][2];
      #pragma unroll
      for (int mi = 0; mi < MPQ; mi++) {
        const int row = wr*(MT*16) + (mq*MPQ+mi)*16 + lane15;
        #pragma unroll
        for (int ks = 0; ks < 2; ks++) {
          const int b = (ks*4 + lgrp) ^ (row & 7);
          af[mi][ks] = *reinterpret_cast<const bf16x8*>(rdA + (row*8 + b)*16);
        }
      }
      if (kt+1 < NT) STG(kn, wrA, wrB, 2+mq);
      #pragma unroll
      for (int mi = 0; mi < MPQ; mi++)
        #pragma unroll
        for (int ni = 0; ni < 4; ni++)
          #pragma unroll
          for (int ks = 0; ks < 2; ks++)
            acc[mq*MPQ+mi][ni] = __builtin_amdgcn_mfma_f32_16x16x32_bf16(
                af[mi][ks], bfr[ni][ks], acc[mq*MPQ+mi][ni], 0, 0, 0);
    }
    if (kt+1 < NT) {
      __builtin_amdgcn_s_barrier();
      if (kt+2 < NT) {
        STG((kt+2) << 6, rdA, rdB, 0);
        asm volatile("s_waitcnt vmcnt(2)" ::: "memory");
      } else {
        asm volatile("s_waitcnt vmcnt(0)" ::: "memory");
      }
      __builtin_amdgcn_s_barrier();
      __builtin_amdgcn_sched_barrier(0);
    }
  }
  #undef STG

  #pragma unroll
  for (int ni = 0; ni < 4; ni++) {
    const int col = n0 + wc*64 + ni*16 + lane15;
    const float bv = bias ? bias[col] : 0.f;
    #pragma unroll
    for (int mi = 0; mi < MT; mi++) {
      #pragma unroll
      for (int r = 0; r < 4; r++) {
        const int row = m0 + wr*(MT*16) + mi*16 + lgrp*4 + r;
        float v = acc[mi][ni][r] + bv;
        if (EPI == 1) {
          if (col < 128) ((float*)Cout)[(size_t)row*128 + col] = v;
          else {
            const float gs = 1.f/(1.f+__expf(-v));
            ((short*)e_g)[(size_t)row*1024 + col - 128] = (short)f2bf(gs);
          }
        } else {
          float* o = (float*)Cout;
          o[(size_t)row*N + col] = v + o[(size_t)row*N + col];
        }
      }
    }
  }
}

// ====== Fused W_O + C_w combine: out = x + g*(attn@WO+bO) + (1-g)*(st@Cw) ===
__global__ __launch_bounds__(256) void wo_comb(
    const short* __restrict__ A1, const short* __restrict__ B1t,   // attn, wT_o
    const short* __restrict__ A2, const short* __restrict__ B2t,   // st, wT_c
    const float* __restrict__ bias, const float* __restrict__ e_x,
    const short* __restrict__ e_g, float* __restrict__ Cout)
{
  constexpr int ABY = 8192;      // 64*64*2
  constexpr int STR = ABY + 16384;
  extern __shared__ char lds[];
  const int tid = threadIdx.x;
  const int ln = tid & 63, w = tid >> 6;
  const int wr = w >> 1, wc = w & 1;
  const int lane15 = ln & 15, lgrp = ln >> 4;
  const int K = 1024, N = 1024;

  const int gx = gridDim.x;
  const int nwg = gx * gridDim.y;
  int id = blockIdx.y * gx + blockIdx.x;
  if ((nwg & 7) == 0) { const int cpx = nwg >> 3; id = (id & 7) * cpx + (id >> 3); }
  const int m0 = (id / gx) * 64, n0 = (id % gx) * 128;

  f32x4 acc1[2][4], acc2[2][4];
  #pragma unroll
  for (int i=0;i<2;i++)
    #pragma unroll
    for (int j=0;j<4;j++){ acc1[i][j] = (f32x4){0.f,0.f,0.f,0.f}; acc2[i][j] = (f32x4){0.f,0.f,0.f,0.f}; }

  #define STGW(Asrc_, Bsrc_, AK_, k0_, bufA_, bufB_, p_) { \
    const int slot = (p_)*256 + tid; \
    const int row = slot >> 3, blk = slot & 7; \
    const int sblk = blk ^ (row & 7); \
    if ((p_) < 2) async16(Asrc_ + (size_t)(m0+row)*(AK_) + (k0_) + sblk*8, (bufA_) + slot*16); \
    async16(Bsrc_ + (size_t)(n0+row)*(AK_) + (k0_) + sblk*8, (bufB_) + slot*16); }

  {
    char* bA = lds, *bB = lds + ABY;
    STGW(A1, B1t, K, 0, bA, bB, 0); STGW(A1, B1t, K, 0, bA, bB, 1);
    STGW(A1, B1t, K, 0, bA, bB, 2); STGW(A1, B1t, K, 0, bA, bB, 3);
    { char* cA = lds + STR, *cB = cA + ABY; STGW(A1, B1t, K, 64, cA, cB, 0); }
    asm volatile("s_waitcnt vmcnt(0)" ::: "memory");
    __builtin_amdgcn_s_barrier();
    __builtin_amdgcn_sched_barrier(0);
  }

  const int NT = 16;
  for (int kt = 0; kt < NT; ++kt) {
    const int cur = kt & 1;
    char* rdA = lds + cur*STR;   char* rdB = rdA + ABY;
    char* wrA = lds + (cur^1)*STR; char* wrB = wrA + ABY;
    const int kn = (kt+1) << 6;
    bf16x8 bfr[4][2];
    #pragma unroll
    for (int ni = 0; ni < 4; ni++) {
      const int row = wc*64 + ni*16 + lane15;
      #pragma unroll
      for (int ks = 0; ks < 2; ks++) {
        const int b = (ks*4 + lgrp) ^ (row & 7);
        bfr[ni][ks] = *reinterpret_cast<const bf16x8*>(rdB + (row*8 + b)*16);
      }
    }
    if (kt+1 < NT) STGW(A1, B1t, K, kn, wrA, wrB, 1);
    #pragma unroll
    for (int mq = 0; mq < 2; ++mq) {
      bf16x8 af[2];
      {
        const int row = wr*32 + mq*16 + lane15;
        #pragma unroll
        for (int ks = 0; ks < 2; ks++) {
          const int b = (ks*4 + lgrp) ^ (row & 7);
          af[ks] = *reinterpret_cast<const bf16x8*>(rdA + (row*8 + b)*16);
        }
      }
      if (kt+1 < NT) STGW(A1, B1t, K, kn, wrA, wrB, 2+mq);
      #pragma unroll
      for (int ni = 0; ni < 4; ni++)
        #pragma unroll
        for (int ks = 0; ks < 2; ks++)
          acc1[mq][ni] = __builtin_amdgcn_mfma_f32_16x16x32_bf16(
              af[ks], bfr[ni][ks], acc1[mq][ni], 0, 0, 0);
    }
    if (kt+1 < NT) {
      __builtin_amdgcn_s_barrier();
      if (kt+2 < NT) {
        STGW(A1, B1t, K, (kt+2) << 6, rdA, rdB, 0);
        asm volatile("s_waitcnt vmcnt(2)" ::: "memory");
      } else {
        asm volatile("s_waitcnt vmcnt(0)" ::: "memory");
      }
      __builtin_amdgcn_s_barrier();
      __builtin_amdgcn_sched_barrier(0);
    }
  }

  // ---- phase 2: acc2 = st @ Cw (K2 = 128, two 64-K tiles, no pipeline) ----
  __builtin_amdgcn_s_barrier();
  {
    char* bA0 = lds,       *bB0 = lds + ABY;
    char* bA1 = lds + STR, *bB1 = bA1 + ABY;
    STGW(A2, B2t, 128, 0,  bA0, bB0, 0); STGW(A2, B2t, 128, 0,  bA0, bB0, 1);
    STGW(A2, B2t, 128, 0,  bA0, bB0, 2); STGW(A2, B2t, 128, 0,  bA0, bB0, 3);
    STGW(A2, B2t, 128, 64, bA1, bB1, 0); STGW(A2, B2t, 128, 64, bA1, bB1, 1);
    STGW(A2, B2t, 128, 64, bA1, bB1, 2); STGW(A2, B2t, 128, 64, bA1, bB1, 3);
    asm volatile("s_waitcnt vmcnt(0)" ::: "memory");
    __builtin_amdgcn_s_barrier();
  }
  #pragma unroll
  for (int t2 = 0; t2 < 2; ++t2) {
    char* rdA = lds + t2*STR; char* rdB = rdA + ABY;
    bf16x8 bfr2[4][2];
    #pragma unroll
    for (int ni = 0; ni < 4; ni++) {
      const int brow = wc*64 + ni*16 + lane15;
      #pragma unroll
      for (int ks = 0; ks < 2; ks++) {
        const int b = (ks*4 + lgrp) ^ (brow & 7);
        bfr2[ni][ks] = *reinterpret_cast<const bf16x8*>(rdB + (brow*8 + b)*16);
      }
    }
    #pragma unroll
    for (int mi = 0; mi < 2; mi++) {
      bf16x8 af[2];
      const int row = wr*32 + mi*16 + lane15;
      #pragma unroll
      for (int ks = 0; ks < 2; ks++) {
        const int b = (ks*4 + lgrp) ^ (row & 7);
        af[ks] = *reinterpret_cast<const bf16x8*>(rdA + (row*8 + b)*16);
      }
      #pragma unroll
      for (int ni = 0; ni < 4; ni++)
        #pragma unroll
        for (int ks = 0; ks < 2; ks++)
          acc2[mi][ni] = __builtin_amdgcn_mfma_f32_16x16x32_bf16(af[ks], bfr2[ni][ks], acc2[mi][ni], 0, 0, 0);
    }
  }
  #undef STGW

  #pragma unroll
  for (int ni = 0; ni < 4; ni++) {
    const int col = n0 + wc*64 + ni*16 + lane15;
    const float bv = bias[col];
    #pragma unroll
    for (int mi = 0; mi < 2; mi++) {
      #pragma unroll
      for (int r = 0; r < 4; r++) {
        const int row = m0 + wr*32 + mi*16 + lgrp*4 + r;
        const float g = bf2f(e_g[(size_t)row*1024 + col]);
        Cout[(size_t)row*N + col] = e_x[(size_t)row*1024 + col]
            + g*(acc1[mi][ni][r] + bv) + (1.f-g)*acc2[mi][ni][r];
      }
    }
  }
}

// ---------------- Flash sliding-window attention (MFMA, bf16) ---------------
#define ATS 72
__global__ __launch_bounds__(256) void attn_mfma(const short* __restrict__ qkv,
                                                 short* __restrict__ attn_out)
{
  __shared__ short Qs[64*ATS];
  __shared__ short Ks[64*ATS];
  __shared__ short Vt[64*ATS];
  __shared__ short Ps[4][16*ATS];
  const int tid = threadIdx.x;
  const int ln = tid & 63, w = tid >> 6;
  const int qt0 = (blockIdx.x >> 4) * 64;
  const int h = blockIdx.x & 15;

  {
    const int jr = tid >> 3, d0 = (tid & 7) * 8;
    #pragma unroll
    for (int p = 0; p < 2; p++) {
      const int j = jr + p*32;
      const bf16x8 v = *reinterpret_cast<const bf16x8*>(&qkv[(size_t)(qt0 + j)*3072 + h*64 + d0]);
      const int blk = (d0 >> 3) ^ (j & 7);
      *reinterpret_cast<bf16x8*>(&Qs[j*ATS + blk*8]) = v;
    }
  }

  float mrow[4], lrow[4];
  f32x4 oacc[4];
  #pragma unroll
  for (int r=0;r<4;r++){ mrow[r] = -1e30f; lrow[r] = 0.f; }
  #pragma unroll
  for (int df=0;df<4;df++) oacc[df] = (f32x4){0.f,0.f,0.f,0.f};

  const int qrow_lane = w*16 + (ln>>4)*4;
  const int qtile = qt0 >> 6;
  const int cstart = (qtile >= 4) ? 0 : (4 - qtile);

  for (int c = cstart; c < 5; c++) {
    const int cs = qt0 - 256 + c*64;
    {
      const int jr = tid >> 3, d0 = (tid & 7) * 8;
      #pragma unroll
      for (int p = 0; p < 2; p++) {
        const int j = jr + p*32;
        const size_t krow = (size_t)(cs + j)*3072 + h*64;
        const bf16x8 kv = *reinterpret_cast<const bf16x8*>(&qkv[krow + 1024 + d0]);
        const int blk = (d0>>3) ^ (j & 7);
        *reinterpret_cast<bf16x8*>(&Ks[j*ATS + blk*8]) = kv;
        const bf16x8 vv = *reinterpret_cast<const bf16x8*>(&qkv[krow + 2048 + d0]);
        #pragma unroll
        for (int i = 0; i < 8; i++) {
          const int d = d0 + i;
          const int jb = (j >> 3) ^ ((d >> 3) & 7);
          Vt[d*ATS + jb*8 + (j & 7)] = ((const short*)&vv)[i];
        }
      }
    }
    __syncthreads();

    bf16x8 aq[2];
    #pragma unroll
    for (int ks=0; ks<2; ks++){
      const int row = w*16 + (ln & 15);
      const int b = (ks*4 + (ln>>4)) ^ (row & 7);
      aq[ks] = *reinterpret_cast<const bf16x8*>(&Qs[row*ATS + b*8]);
    }
    float sv[4][4];
    #pragma unroll
    for (int nf=0; nf<4; nf++){
      const int krow = nf*16 + (ln & 15);
      f32x4 s = (f32x4){0.f,0.f,0.f,0.f};
      #pragma unroll
      for (int ks=0; ks<2; ks++){
        const int b = (ks*4 + (ln>>4)) ^ (krow & 7);
        const bf16x8 bk = *reinterpret_cast<const bf16x8*>(&Ks[krow*ATS + b*8]);
        s = __builtin_amdgcn_mfma_f32_16x16x32_bf16(aq[ks], bk, s, 0, 0, 0);
      }
      const int k_abs = cs + nf*16 + (ln & 15);
      #pragma unroll
      for (int r=0;r<4;r++){
        const int t_abs = qt0 + qrow_lane + r;
        const bool valid = (k_abs <= t_abs) && (k_abs >= t_abs - 255);
        sv[nf][r] = valid ? s[r]*0.125f : -1e30f;
      }
    }
    float cm[4], alpha[4], rs[4];
    #pragma unroll
    for (int r=0;r<4;r++){
      cm[r] = fmaxf(fmaxf(sv[0][r],sv[1][r]), fmaxf(sv[2][r],sv[3][r]));
      #pragma unroll
      for (int off=1; off<16; off<<=1) cm[r] = fmaxf(cm[r], __shfl_xor(cm[r], off));
      const float mnew = fmaxf(mrow[r], cm[r]);
      alpha[r] = __expf(mrow[r] - mnew);
      mrow[r] = mnew;
      rs[r] = 0.f;
    }
    #pragma unroll
    for (int nf=0; nf<4; nf++){
      const int pcol = nf*16 + (ln & 15);
      #pragma unroll
      for (int r=0;r<4;r++){
        const float p = (sv[nf][r] <= -1e29f) ? 0.f : __expf(sv[nf][r] - mrow[r]);
        rs[r] += p;
        const int prow = (ln>>4)*4 + r;
        const int pb = (pcol>>3) ^ (prow & 7);
        Ps[w][prow*ATS + pb*8 + (pcol & 7)] = (short)f2bf(p);
      }
    }
    #pragma unroll
    for (int r=0;r<4;r++){
      #pragma unroll
      for (int off=1; off<16; off<<=1) rs[r] += __shfl_xor(rs[r], off);
      lrow[r] = lrow[r]*alpha[r] + rs[r];
      #pragma unroll
      for (int df=0; df<4; df++) oacc[df][r] *= alpha[r];
    }
    bf16x8 ap[2];
    #pragma unroll
    for (int ks=0; ks<2; ks++){
      const int prow = (ln & 15);
      const int b = (ks*4 + (ln>>4)) ^ (prow & 7);
      ap[ks] = *reinterpret_cast<const bf16x8*>(&Ps[w][prow*ATS + b*8]);
    }
    #pragma unroll
    for (int df=0; df<4; df++){
      const int vrow = df*16 + (ln & 15);
      #pragma unroll
      for (int ks=0; ks<2; ks++){
        const int b = (ks*4 + (ln>>4)) ^ ((vrow>>3) & 7);
        const bf16x8 bv = *reinterpret_cast<const bf16x8*>(&Vt[vrow*ATS + b*8]);
        oacc[df] = __builtin_amdgcn_mfma_f32_16x16x32_bf16(ap[ks], bv, oacc[df], 0, 0, 0);
      }
    }
    __syncthreads();
  }

  #pragma unroll
  for (int df=0; df<4; df++)
    #pragma unroll
    for (int r=0; r<4; r++){
      const int t = qt0 + qrow_lane + r;
      const int d = df*16 + (ln & 15);
      attn_out[(size_t)t*1024 + h*64 + d] = (short)f2bf(oacc[df][r] / lrow[r]);
    }
}

// ---------------- SSM scan as 16-tap convolution (compact drive) ------------
__global__ __launch_bounds__(256) void scan_kernel(const float* __restrict__ drive,
    const float* __restrict__ Aa, short* __restrict__ states)
{
  const int idx = blockIdx.x*256 + threadIdx.x;
  const int t = idx >> 7, s = idx & 127;
  const float a = Aa[s];
  float acc = 0.f, pw = 1.f;
  const int kmax = (t+1 < 16) ? (t+1) : 16;
  for (int k=0;k<kmax;k++){
    acc = fmaf(pw, drive[(size_t)(t-k)*128 + s], acc);
    pw *= a;
  }
  states[idx] = (short)f2bf(acc);
}

extern "C" void kernel_launch(void* const* d_in, const int* in_sizes, int n_in,
                              void* d_out, int out_size, void* d_ws, size_t ws_size,
                              hipStream_t stream)
{
  const float* x     = (const float*)d_in[0];
  const float* ln1_g = (const float*)d_in[1];
  const float* ln1_b = (const float*)d_in[2];
  const float* ln2_g = (const float*)d_in[3];
  const float* ln2_b = (const float*)d_in[4];
  const float* W_qkv = (const float*)d_in[5];
  const float* W_O   = (const float*)d_in[6];
  const float* b_O   = (const float*)d_in[7];
  const float* W_ug  = (const float*)d_in[8];
  const float* b_ug  = (const float*)d_in[9];
  const float* B_w   = (const float*)d_in[10];
  const float* A     = (const float*)d_in[11];
  const float* C_w   = (const float*)d_in[12];
  const float* W1    = (const float*)d_in[13];
  const float* b1    = (const float*)d_in[14];
  const float* W2    = (const float*)d_in[15];
  const float* b2    = (const float*)d_in[16];
  float* out = (float*)d_out;
  char* ws = (char*)d_ws;

  short* qkv_bf = (short*)(ws + 0);          // 24MB
  short* attn_bf= (short*)(ws + 25165824);   // 8MB
  short* xn_bf  = (short*)(ws + 33554432);   // 8MB (h aliases)
  short* g_bf   = (short*)(ws + 41943040);   // 8MB  gate (sigmoid, bf16)
  float* drive  = (float*)(ws + 50331648);   // 2MB  fp32 [4096][128]
  short* st_bf  = (short*)(ws + 52428800);   // 1MB
  float* b_all  = (float*)(ws + 53477376);   // 64KB
  short* wT_qkv = (short*)(ws + 53542912);   // 6MB
  short* wT_o   = (short*)(ws + 59834368);   // 2MB
  short* wT_ug  = (short*)(ws + 61931520);   // 2.25MB
  short* wT_c   = (short*)(ws + 64290816);   // 0.25MB
  short* wT_1   = (short*)(ws + 64552960);   // 8MB
  short* wT_2   = (short*)(ws + 72941568);   // 8MB
  short* mid_bf = (short*)(ws + 0);          // 32MB alias (dead qkv+attn)
  short* h_bf   = xn_bf;

  static bool attr_done = false;
  if (!attr_done) {
    hipFuncSetAttribute((const void*)gemm256<0>, hipFuncAttributeMaxDynamicSharedMemorySize, 131072);
    hipFuncSetAttribute((const void*)gemm256<1>, hipFuncAttributeMaxDynamicSharedMemorySize, 131072);
    hipFuncSetAttribute((const void*)(gemm128<2,1>), hipFuncAttributeMaxDynamicSharedMemorySize, 49152);
    hipFuncSetAttribute((const void*)(gemm128<2,3>), hipFuncAttributeMaxDynamicSharedMemorySize, 49152);
    hipFuncSetAttribute((const void*)wo_comb, hipFuncAttributeMaxDynamicSharedMemorySize, 49152);
    attr_done = true;
  }

  prep_weights<<<13585, 256, 0, stream>>>(W_qkv, W_O, W_ug, B_w, C_w, W1, W2, b_ug,
                                          wT_qkv, wT_o, wT_ug, wT_c, wT_1, wT_2, b_all);

  ln_bf16<<<4096, 256, 0, stream>>>(x, ln1_g, ln1_b, xn_bf);
  gemm256<0><<<dim3(12,16), 512, 131072, stream>>>(xn_bf, wT_qkv, nullptr, qkv_bf, 4096, 3072, 1024);
  attn_mfma<<<1024, 256, 0, stream>>>(qkv_bf, attn_bf);
  gemm128<2,1><<<dim3(9,64), 256, 49152, stream>>>(xn_bf, wT_ug, b_ug, g_bf, drive, 4096, 1152, 1024);
  scan_kernel<<<2048, 256, 0, stream>>>(drive, A, st_bf);
  wo_comb<<<dim3(8,64), 256, 49152, stream>>>(attn_bf, wT_o, st_bf, wT_c, b_O, x, g_bf, out);
  ln_bf16<<<4096, 256, 0, stream>>>(out, ln2_g, ln2_b, h_bf);
  gemm256<1><<<dim3(16,16), 512, 131072, stream>>>(h_bf, wT_1, b1, mid_bf, 4096, 4096, 1024);
  gemm128<2,3><<<dim3(8,64), 256, 49152, stream>>>(mid_bf, wT_2, b2, nullptr, out, 4096, 1024, 4096);
}